// Round 3
// baseline (1578.518 us; speedup 1.0000x reference)
//
#include <hip/hip_runtime.h>
#include <cmath>
#include <cstdint>
#include <cstddef>

#define HID 64
#define NGR 128            // B graphs
#define EDGES 1048576      // B * 1024 * 8
#define EPG 8192           // edges per graph
#define VALID (1u << 20)

// ---------- pack edges + degree + dinv + zero sums/readout (block = graph) ----------
__global__ __launch_bounds__(256) void pack_init(
    const int* __restrict__ ei, uint32_t* __restrict__ packed,
    float* __restrict__ dinv_g, float* __restrict__ sums3,
    float* __restrict__ readout) {
  __shared__ int hist[1024];
  int b = blockIdx.x, t = threadIdx.x;
  for (int i = t; i < 1024; i += 256) hist[i] = 0;
  __syncthreads();
  int ebase = b * EPG, nbase = b << 10;
  for (int e = t; e < EPG; e += 256) {
    uint32_t s = (uint32_t)(ei[ebase + e] - nbase);
    uint32_t d = (uint32_t)(ei[EDGES + ebase + e] - nbase);
    packed[ebase + e] = s | (d << 10) | VALID;
    atomicAdd(&hist[(int)d], 1);
  }
  __syncthreads();
  for (int i = t; i < 1024; i += 256)
    dinv_g[(b << 10) + i] = rsqrtf((float)hist[i] + 1.0f);
  if (b < 3 && t < 128) sums3[b * 128 + t] = 0.0f;
  if (t < 128) readout[b * 128 + t] = 0.0f;
}

// ---------------- xw = X @ W  (X:[N,DIN], W:[DIN,64]) ----------------
template<int DIN>
__global__ __launch_bounds__(256) void gemm_xw(
    const float* __restrict__ X, const float* __restrict__ W,
    float* __restrict__ XW, int n_nodes) {
  __shared__ float sW[32 * HID];       // 8 KB
  __shared__ float sXT[32 * 132];      // 16.5 KB
  const int t = threadIdx.x;
  const int cq = t & 15, ng = t >> 4;
  const int c4 = cq * 4;
  const int node0 = blockIdx.x * 128;
  float acc[8][4];
#pragma unroll
  for (int n = 0; n < 8; n++) { acc[n][0]=0.f; acc[n][1]=0.f; acc[n][2]=0.f; acc[n][3]=0.f; }

  for (int k0 = 0; k0 < DIN; k0 += 32) {
    ((float4*)sW)[t * 2 + 0] = ((const float4*)(W + (size_t)k0 * HID))[t * 2 + 0];
    ((float4*)sW)[t * 2 + 1] = ((const float4*)(W + (size_t)k0 * HID))[t * 2 + 1];
    {
      int i4 = (t & 7) * 4;
      int nl = t >> 3;
#pragma unroll
      for (int rep = 0; rep < 4; rep++) {
        int nn = nl + rep * 32;
        int g = node0 + nn;
        float4 v = make_float4(0.f, 0.f, 0.f, 0.f);
        if (g < n_nodes) v = *(const float4*)(X + (size_t)g * DIN + k0 + i4);
        sXT[(i4 + 0) * 132 + nn] = v.x;
        sXT[(i4 + 1) * 132 + nn] = v.y;
        sXT[(i4 + 2) * 132 + nn] = v.z;
        sXT[(i4 + 3) * 132 + nn] = v.w;
      }
    }
    __syncthreads();
#pragma unroll 4
    for (int i = 0; i < 32; i++) {
      float4 w = *(const float4*)(sW + i * HID + c4);
      const float* xr = sXT + i * 132 + ng * 8;
      float4 xa = *(const float4*)xr;
      float4 xb = *(const float4*)(xr + 4);
      float xn[8] = {xa.x, xa.y, xa.z, xa.w, xb.x, xb.y, xb.z, xb.w};
#pragma unroll
      for (int n = 0; n < 8; n++) {
        acc[n][0] = fmaf(xn[n], w.x, acc[n][0]);
        acc[n][1] = fmaf(xn[n], w.y, acc[n][1]);
        acc[n][2] = fmaf(xn[n], w.z, acc[n][2]);
        acc[n][3] = fmaf(xn[n], w.w, acc[n][3]);
      }
    }
    __syncthreads();
  }
#pragma unroll
  for (int n = 0; n < 8; n++) {
    int g = node0 + ng * 8 + n;
    if (g < n_nodes)
      *(float4*)(XW + (size_t)g * HID + c4) =
          make_float4(acc[n][0], acc[n][1], acc[n][2], acc[n][3]);
  }
}

// ---------- fused aggregate (pre-scaled) + self-loop + bias + BN sums ----------
// 32 channel-pair splits x 128 graphs; LDS = 20 KB -> 8 blocks/CU (100% occ)
__global__ __launch_bounds__(256, 8) void edge_agg(
    const uint32_t* __restrict__ packed, const float* __restrict__ dinv_g,
    const float* __restrict__ xw, const float* __restrict__ bias,
    float* __restrict__ h, float* __restrict__ sums, int npg) {
  __shared__ float xws[1024 * 2];    // 8 KB  (xw * dinv, pre-scaled)
  __shared__ float accs[1024 * 2];   // 8 KB
  __shared__ float dv[1024];         // 4 KB
  int g = blockIdx.x & 127;
  int q = blockIdx.x >> 7;           // 0..31
  int c0 = q * 2;
  int t = threadIdx.x;
  int gbase = g * npg;
  for (int i = t; i < npg; i += 256) {
    float dvi = dinv_g[gbase + i];
    dv[i] = dvi;
    float2 v = *(const float2*)(xw + (size_t)(gbase + i) * HID + c0);
    xws[i * 2 + 0] = v.x * dvi;
    xws[i * 2 + 1] = v.y * dvi;
    accs[i * 2 + 0] = 0.0f;
    accs[i * 2 + 1] = 0.0f;
  }
  __syncthreads();
  const uint4* pe4 = (const uint4*)(packed + (size_t)g * EPG);
  int c = t & 1, j = t >> 1;         // j in 0..127
  for (int it = j; it < EPG / 4; it += 128) {
    uint4 pk4 = pe4[it];
    uint32_t pks[4] = {pk4.x, pk4.y, pk4.z, pk4.w};
#pragma unroll
    for (int m = 0; m < 4; m++) {
      uint32_t pk = pks[m];
      if (pk & VALID) {
        int s = pk & 1023, d = (pk >> 10) & 1023;
        atomicAdd(&accs[d * 2 + c], xws[s * 2 + c]);
      }
    }
  }
  __syncthreads();
  float2 bv = *(const float2*)(bias + c0);
  float S0 = 0, S1 = 0, Q0 = 0, Q1 = 0;
  for (int i = t; i < npg; i += 256) {
    float dvi = dv[i];
    float h0 = (accs[i * 2 + 0] + xws[i * 2 + 0]) * dvi + bv.x;
    float h1 = (accs[i * 2 + 1] + xws[i * 2 + 1]) * dvi + bv.y;
    *(float2*)(h + (size_t)(gbase + i) * HID + c0) = make_float2(h0, h1);
    S0 += h0; S1 += h1; Q0 += h0 * h0; Q1 += h1 * h1;
  }
#pragma unroll
  for (int m = 1; m < 64; m <<= 1) {
    S0 += __shfl_xor(S0, m); S1 += __shfl_xor(S1, m);
    Q0 += __shfl_xor(Q0, m); Q1 += __shfl_xor(Q1, m);
  }
  if ((t & 63) == 0) {
    atomicAdd(&sums[c0 + 0], S0);
    atomicAdd(&sums[c0 + 1], S1);
    atomicAdd(&sums[64 + c0 + 0], Q0);
    atomicAdd(&sums[64 + c0 + 1], Q1);
  }
}

// ---------- per-graph fused: BN+ReLU+score -> topk -> pool+readout -> remap+deg ----------
__global__ __launch_bounds__(512) void post_kernel(
    const float* __restrict__ h, const float* __restrict__ sums,
    const float* __restrict__ gamma, const float* __restrict__ beta,
    const float* __restrict__ p, float* __restrict__ xpool,
    uint32_t* __restrict__ packed, float* __restrict__ dinv_g,
    float* __restrict__ readout,
    const float* __restrict__ Wm, const float* __restrict__ bm,
    float* __restrict__ out,
    int npg, int k, float inv_n) {
  __shared__ float ssc[64], ssh[64], sp[64];
  __shared__ float invPn;
  __shared__ float __align__(16) sscore[1024];
  __shared__ int slmap[1024];
  __shared__ int stmp[1024];            // sel (pass B) then hist (pass C)
  __shared__ float redS[8 * 64], redM[8 * 64];
  __shared__ float fro[128];
  int b = blockIdx.x, t = threadIdx.x;
  int gbase = b * npg;
  if (t < 64) {
    float mu = sums[t] * inv_n;
    float var = fmaxf(sums[64 + t] * inv_n - mu * mu, 0.0f);
    float sc = rsqrtf(var + 1e-5f) * gamma[t];
    ssc[t] = sc; ssh[t] = beta[t] - mu * sc; sp[t] = p[t];
  }
  for (int i = t; i < 1024; i += 512) sscore[i] = -INFINITY;
  __syncthreads();
  if (t == 0) {
    float s = 0.0f;
    for (int i = 0; i < 64; i++) s += sp[i] * sp[i];
    invPn = rsqrtf(s);
  }
  __syncthreads();
  // ---- pass A: scores (4 threads per row) ----
  int q = t & 3, row0 = t >> 2, cb = q * 16;
  for (int r = row0; r < npg; r += 128) {
    const float* hr = h + (size_t)(gbase + r) * HID + cb;
    float partial = 0.0f;
#pragma unroll
    for (int u = 0; u < 4; u++) {
      float4 v = *(const float4*)(hr + u * 4);
      int ch = cb + u * 4;
      float y0 = fmaxf(fmaf(v.x, ssc[ch + 0], ssh[ch + 0]), 0.0f);
      float y1 = fmaxf(fmaf(v.y, ssc[ch + 1], ssh[ch + 1]), 0.0f);
      float y2 = fmaxf(fmaf(v.z, ssc[ch + 2], ssh[ch + 2]), 0.0f);
      float y3 = fmaxf(fmaf(v.w, ssc[ch + 3], ssh[ch + 3]), 0.0f);
      partial += y0 * sp[ch + 0] + y1 * sp[ch + 1] + y2 * sp[ch + 2] + y3 * sp[ch + 3];
    }
    partial += __shfl_xor(partial, 1);
    partial += __shfl_xor(partial, 2);
    if (q == 0) sscore[r] = partial * invPn;
  }
  __syncthreads();
  // ---- topk: rank counting, 2 slots/thread over padded 1024 ----
  float my[2]; int rk[2];
#pragma unroll
  for (int m = 0; m < 2; m++) { my[m] = sscore[t * 2 + m]; rk[m] = 0; }
  for (int jb = 0; jb < 256; jb++) {
    float4 v = ((const float4*)sscore)[jb];
    int j0 = jb * 4;
#pragma unroll
    for (int m = 0; m < 2; m++) {
      int gi = t * 2 + m;
      rk[m] += (v.x > my[m]) || (v.x == my[m] && (j0 + 0) < gi);
      rk[m] += (v.y > my[m]) || (v.y == my[m] && (j0 + 1) < gi);
      rk[m] += (v.z > my[m]) || (v.z == my[m] && (j0 + 2) < gi);
      rk[m] += (v.w > my[m]) || (v.w == my[m] && (j0 + 3) < gi);
    }
  }
#pragma unroll
  for (int m = 0; m < 2; m++) {
    int i = t * 2 + m;
    bool sel = (i < npg) && (rk[m] < k);
    slmap[i] = sel ? rk[m] : -1;
    if (sel) stmp[rk[m]] = i;
  }
  __syncthreads();
  // ---- pass B: gather selected rows, y*tanh(score), write xpool, mean/max ----
  float S[16], M[16];
#pragma unroll
  for (int i = 0; i < 16; i++) { S[i] = 0.0f; M[i] = -INFINITY; }
  for (int r = row0; r < k; r += 128) {
    int old = stmp[r];
    float tn = tanhf(sscore[old]);
    const float* hr = h + (size_t)(gbase + old) * HID + cb;
    float* xo = xpool ? (xpool + (size_t)(b * k + r) * HID + cb) : nullptr;
#pragma unroll
    for (int u = 0; u < 4; u++) {
      float4 v = *(const float4*)(hr + u * 4);
      int ch = cb + u * 4;
      float y0 = fmaxf(fmaf(v.x, ssc[ch + 0], ssh[ch + 0]), 0.0f) * tn;
      float y1 = fmaxf(fmaf(v.y, ssc[ch + 1], ssh[ch + 1]), 0.0f) * tn;
      float y2 = fmaxf(fmaf(v.z, ssc[ch + 2], ssh[ch + 2]), 0.0f) * tn;
      float y3 = fmaxf(fmaf(v.w, ssc[ch + 3], ssh[ch + 3]), 0.0f) * tn;
      if (xo) *(float4*)(xo + u * 4) = make_float4(y0, y1, y2, y3);
      int i0 = u * 4;
      S[i0 + 0] += y0; S[i0 + 1] += y1; S[i0 + 2] += y2; S[i0 + 3] += y3;
      M[i0 + 0] = fmaxf(M[i0 + 0], y0); M[i0 + 1] = fmaxf(M[i0 + 1], y1);
      M[i0 + 2] = fmaxf(M[i0 + 2], y2); M[i0 + 3] = fmaxf(M[i0 + 3], y3);
    }
  }
#pragma unroll
  for (int m = 4; m < 64; m <<= 1) {
#pragma unroll
    for (int i = 0; i < 16; i++) {
      S[i] += __shfl_xor(S[i], m);
      M[i] = fmaxf(M[i], __shfl_xor(M[i], m));
    }
  }
  {
    int lane = t & 63, w = t >> 6;
    if (lane < 4) {
#pragma unroll
      for (int i = 0; i < 16; i++) {
        redS[w * 64 + lane * 16 + i] = S[i];
        redM[w * 64 + lane * 16 + i] = M[i];
      }
    }
  }
  __syncthreads();
  if (t < 64) {
    float Sg = 0.0f, Mg = -INFINITY;
    for (int w = 0; w < 8; w++) {
      Sg += redS[w * 64 + t];
      Mg = fmaxf(Mg, redM[w * 64 + t]);
    }
    float mean = Sg / (float)k;
    float* ro = readout + (size_t)b * 128;
    if (out == nullptr) {
      ro[t] += mean;
      ro[64 + t] += Mg;
    } else {
      fro[t] = ro[t] + mean;
      fro[64 + t] = ro[64 + t] + Mg;
    }
  }
  __syncthreads();
  if (out != nullptr && t < 10) {
    float acc = bm[t];
    for (int c = 0; c < 128; c++) acc = fmaf(fro[c], Wm[c * 10 + t], acc);
    out[b * 10 + t] = acc;
  }
  // ---- pass C: remap edges + new degree + dinv for next layer ----
  if (xpool != nullptr) {
    for (int i = t; i < 1024; i += 512) stmp[i] = 0;
    __syncthreads();
    uint32_t* pe = packed + (size_t)b * EPG;
    for (int e = t; e < EPG; e += 512) {
      uint32_t pk = pe[e];
      uint32_t outpk = 0;
      if (pk & VALID) {
        int ns = slmap[pk & 1023], nd = slmap[(pk >> 10) & 1023];
        if (ns >= 0 && nd >= 0) {
          outpk = (uint32_t)ns | ((uint32_t)nd << 10) | VALID;
          atomicAdd(&stmp[nd], 1);
        }
      }
      pe[e] = outpk;
    }
    __syncthreads();
    for (int r = t; r < k; r += 512)
      dinv_g[(size_t)b * k + r] = rsqrtf((float)stmp[r] + 1.0f);
  }
}

extern "C" void kernel_launch(void* const* d_in, const int* in_sizes, int n_in,
                              void* d_out, int out_size, void* d_ws, size_t ws_size,
                              hipStream_t stream) {
  (void)in_sizes; (void)n_in; (void)out_size; (void)ws_size;
  const float* x  = (const float*)d_in[0];
  const int*   ei = (const int*)d_in[1];
  const float* Wk[3]  = {(const float*)d_in[2],  (const float*)d_in[7],  (const float*)d_in[12]};
  const float* bk[3]  = {(const float*)d_in[3],  (const float*)d_in[8],  (const float*)d_in[13]};
  const float* gk[3]  = {(const float*)d_in[4],  (const float*)d_in[9],  (const float*)d_in[14]};
  const float* btk[3] = {(const float*)d_in[5],  (const float*)d_in[10], (const float*)d_in[15]};
  const float* pk[3]  = {(const float*)d_in[6],  (const float*)d_in[11], (const float*)d_in[16]};
  const float* Wm = (const float*)d_in[17];
  const float* bm = (const float*)d_in[18];
  float* out = (float*)d_out;

  // ---- workspace carve (floats) ----
  float* ws = (float*)d_ws;
  size_t off = 0;
  auto alloc = [&](size_t nfl) {
    float* ptr = ws + off;
    off += (nfl + 63) & ~(size_t)63;
    return ptr;
  };
  float* bufXW = alloc((size_t)131072 * 64);
  float* bufH  = alloc((size_t)131072 * 64);
  float* bufP  = alloc((size_t)104960 * 64);
  float* dinv_g = alloc(131072);
  uint32_t* packed = (uint32_t*)alloc(EDGES);
  float* sums3 = alloc(3 * 128);
  float* readout = alloc(NGR * 2 * HID);

  pack_init<<<NGR, 256, 0, stream>>>(ei, packed, dinv_g, sums3, readout);

  // =============== Block 1: n=1024 -> k=820 ===============
  {
    const int npg = 1024, k = 820, Nc = NGR * npg;
    gemm_xw<128><<<Nc / 128, 256, 0, stream>>>(x, Wk[0], bufXW, Nc);
    edge_agg<<<32 * NGR, 256, 0, stream>>>(packed, dinv_g, bufXW, bk[0], bufH,
                                           sums3, npg);
    post_kernel<<<NGR, 512, 0, stream>>>(bufH, sums3, gk[0], btk[0], pk[0],
                                         bufP, packed, dinv_g, readout,
                                         nullptr, nullptr, nullptr,
                                         npg, k, 1.0f / Nc);
  }
  // =============== Block 2: n=820 -> k=656 ===============
  {
    const int npg = 820, k = 656, Nc = NGR * npg;
    gemm_xw<64><<<Nc / 128, 256, 0, stream>>>(bufP, Wk[1], bufXW, Nc);
    edge_agg<<<32 * NGR, 256, 0, stream>>>(packed, dinv_g, bufXW, bk[1], bufH,
                                           sums3 + 128, npg);
    post_kernel<<<NGR, 512, 0, stream>>>(bufH, sums3 + 128, gk[1], btk[1], pk[1],
                                         bufP, packed, dinv_g, readout,
                                         nullptr, nullptr, nullptr,
                                         npg, k, 1.0f / Nc);
  }
  // =============== Block 3: n=656 -> k=525 ===============
  {
    const int npg = 656, k = 525, Nc = NGR * npg;
    gemm_xw<64><<<Nc / 128, 256, 0, stream>>>(bufP, Wk[2], bufXW, Nc);
    edge_agg<<<32 * NGR, 256, 0, stream>>>(packed, dinv_g, bufXW, bk[2], bufH,
                                           sums3 + 256, npg);
    post_kernel<<<NGR, 512, 0, stream>>>(bufH, sums3 + 256, gk[2], btk[2], pk[2],
                                         nullptr, packed, dinv_g, readout,
                                         Wm, bm, out,
                                         npg, k, 1.0f / Nc);
  }
}

// Round 4
// 1208.184 us; speedup vs baseline: 1.3065x; 1.3065x over previous
//
#include <hip/hip_runtime.h>
#include <cmath>
#include <cstdint>
#include <cstddef>

#define HID 64
#define NGR 128            // B graphs
#define EDGES 1048576      // B * 1024 * 8
#define EPG 8192           // edges per graph
#define VALID (1u << 20)

// ---------- pack edges + degree + dinv + zero sums/readout (block = graph) ----------
__global__ __launch_bounds__(256) void pack_init(
    const int* __restrict__ ei, uint32_t* __restrict__ packed,
    float* __restrict__ dinv_g, float* __restrict__ sums3,
    float* __restrict__ readout) {
  __shared__ int hist[1024];
  int b = blockIdx.x, t = threadIdx.x;
  for (int i = t; i < 1024; i += 256) hist[i] = 0;
  __syncthreads();
  int ebase = b * EPG, nbase = b << 10;
  for (int e = t; e < EPG; e += 256) {
    uint32_t s = (uint32_t)(ei[ebase + e] - nbase);
    uint32_t d = (uint32_t)(ei[EDGES + ebase + e] - nbase);
    packed[ebase + e] = s | (d << 10) | VALID;
    atomicAdd(&hist[(int)d], 1);
  }
  __syncthreads();
  for (int i = t; i < 1024; i += 256)
    dinv_g[(b << 10) + i] = rsqrtf((float)hist[i] + 1.0f);
  if (b < 3 && t < 128) sums3[b * 128 + t] = 0.0f;
  if (t < 128) readout[b * 128 + t] = 0.0f;
}

// ---------- xw^T = (X @ W)^T.  X row-major [N,DIN] (TIN=0) or transposed [DIN,N] (TIN=1).
// Output XWT [64][N] channel-major. grid = N/128 exact.
template<int DIN, bool TIN>
__global__ __launch_bounds__(256) void gemm_xw(
    const float* __restrict__ X, const float* __restrict__ W,
    float* __restrict__ XWT, int n_nodes) {
  __shared__ float sW[32 * HID];       // 8 KB
  __shared__ float sX[32 * 132];       // 16.5 KB  (k-major, node inner, pad 4)
  const int t = threadIdx.x;
  const int cq = t & 15, ng = t >> 4;
  const int c4 = cq * 4;
  const int node0 = blockIdx.x * 128;
  const size_t Nn = (size_t)n_nodes;
  float acc[8][4];
#pragma unroll
  for (int n = 0; n < 8; n++) { acc[n][0]=0.f; acc[n][1]=0.f; acc[n][2]=0.f; acc[n][3]=0.f; }

  for (int k0 = 0; k0 < DIN; k0 += 32) {
    ((float4*)sW)[t * 2 + 0] = ((const float4*)(W + (size_t)k0 * HID))[t * 2 + 0];
    ((float4*)sW)[t * 2 + 1] = ((const float4*)(W + (size_t)k0 * HID))[t * 2 + 1];
    if (TIN) {
      // X is [DIN][N]: coalesced row-segment loads
#pragma unroll
      for (int it = 0; it < 4; it++) {
        int slot = t + it * 256;
        int row = slot >> 5, col4 = (slot & 31) * 4;
        *(float4*)(sX + row * 132 + col4) =
            *(const float4*)(X + (size_t)(k0 + row) * Nn + node0 + col4);
      }
    } else {
      // X is [N][DIN]: row chunk == one full cacheline per 8 lanes
      int i4 = (t & 7) * 4;
      int nl = t >> 3;
#pragma unroll
      for (int rep = 0; rep < 4; rep++) {
        int nn = nl + rep * 32;
        float4 v = *(const float4*)(X + (size_t)(node0 + nn) * DIN + k0 + i4);
        sX[(i4 + 0) * 132 + nn] = v.x;
        sX[(i4 + 1) * 132 + nn] = v.y;
        sX[(i4 + 2) * 132 + nn] = v.z;
        sX[(i4 + 3) * 132 + nn] = v.w;
      }
    }
    __syncthreads();
#pragma unroll 4
    for (int i = 0; i < 32; i++) {
      float4 w = *(const float4*)(sW + i * HID + c4);
      const float* xr = sX + i * 132 + ng * 8;
      float4 xa = *(const float4*)xr;
      float4 xb = *(const float4*)(xr + 4);
      float xn[8] = {xa.x, xa.y, xa.z, xa.w, xb.x, xb.y, xb.z, xb.w};
#pragma unroll
      for (int n = 0; n < 8; n++) {
        acc[n][0] = fmaf(xn[n], w.x, acc[n][0]);
        acc[n][1] = fmaf(xn[n], w.y, acc[n][1]);
        acc[n][2] = fmaf(xn[n], w.z, acc[n][2]);
        acc[n][3] = fmaf(xn[n], w.w, acc[n][3]);
      }
    }
    __syncthreads();
  }
  // transposed store: per (c,wave) stores are 128B-contiguous
#pragma unroll
  for (int cc = 0; cc < 4; cc++) {
    int row = c4 + cc;
    float* o = XWT + (size_t)row * Nn + node0 + ng * 8;
    *(float4*)(o + 0) = make_float4(acc[0][cc], acc[1][cc], acc[2][cc], acc[3][cc]);
    *(float4*)(o + 4) = make_float4(acc[4][cc], acc[5][cc], acc[6][cc], acc[7][cc]);
  }
}

// ---------- fused aggregate (pre-scaled) + self-loop + bias + BN sums ----------
// 8 channel-octet splits x 128 graphs; 1024 thr; LDS ~70KB -> 2 blocks/CU (32 waves)
__global__ __launch_bounds__(1024, 8) void edge_agg(
    const uint32_t* __restrict__ packed, const float* __restrict__ dinv_g,
    const float* __restrict__ xwT, const float* __restrict__ bias,
    float* __restrict__ hT, float* __restrict__ sums, int npg) {
  __shared__ float xws[8 * 1028];    // pre-scaled xw*dinv, stride 1028: 8ch of an edge -> 8 banks
  __shared__ float accs[8 * 1028];
  __shared__ float dv[1024];
  __shared__ float sredS[16], sredQ[16];
  const int g = blockIdx.x & 127;       // same-g splits 128 apart -> same XCD
  const int q = blockIdx.x >> 7;        // 0..7
  const int c0 = q * 8;
  const int t = threadIdx.x;
  const int gbase = g * npg;
  const size_t Nn = (size_t)npg * 128;
  const int npg4 = npg >> 2;

  if (t < npg) dv[t] = dinv_g[gbase + t];
  __syncthreads();
  for (int slot = t; slot < 8 * npg4; slot += 1024) {
    int c = slot / npg4, pos = slot - c * npg4;
    float4 v = *(const float4*)(xwT + (size_t)(c0 + c) * Nn + gbase + pos * 4);
    float4 dd = *(const float4*)(dv + pos * 4);
    v.x *= dd.x; v.y *= dd.y; v.z *= dd.z; v.w *= dd.w;
    *(float4*)(xws + c * 1028 + pos * 4) = v;
    *(float4*)(accs + c * 1028 + pos * 4) = make_float4(0, 0, 0, 0);
  }
  __syncthreads();

  // inner loop: pure ds_read + ds_add, 8 edges/wave-instr
  const uint4* pe4 = (const uint4*)(packed + (size_t)g * EPG);
  {
    const int cch = t & 7;
    const float* xr = xws + cch * 1028;
    float* ar = accs + cch * 1028;
#pragma unroll 2
    for (int it = (t >> 3); it < EPG / 4; it += 128) {
      uint4 pk4 = pe4[it];
      uint32_t pks[4] = {pk4.x, pk4.y, pk4.z, pk4.w};
#pragma unroll
      for (int m = 0; m < 4; m++) {
        uint32_t pk = pks[m];
        if (pk & VALID) {
          int s = pk & 1023, d = (pk >> 10) & 1023;
          atomicAdd((float*)(ar + d), xr[s]);
        }
      }
    }
  }
  __syncthreads();

  // epilogue: h = (acc + xws)*dinv + b, coalesced transposed store + BN sums
  {
    const int ce = t >> 7;            // 0..7 (wave-uniform)
    const int pos0 = t & 127;
    const float bv = bias[c0 + ce];
    float* hrow = hT + (size_t)(c0 + ce) * Nn + gbase;
    const float* xr = xws + ce * 1028;
    const float* ar = accs + ce * 1028;
    float S = 0.0f, Q = 0.0f;
    for (int pos = pos0; pos < npg4; pos += 128) {
      float4 a = *(const float4*)(ar + pos * 4);
      float4 xv = *(const float4*)(xr + pos * 4);
      float4 dd = *(const float4*)(dv + pos * 4);
      float h0 = (a.x + xv.x) * dd.x + bv;
      float h1 = (a.y + xv.y) * dd.y + bv;
      float h2 = (a.z + xv.z) * dd.z + bv;
      float h3 = (a.w + xv.w) * dd.w + bv;
      *(float4*)(hrow + pos * 4) = make_float4(h0, h1, h2, h3);
      S += h0 + h1 + h2 + h3;
      Q += h0 * h0 + h1 * h1 + h2 * h2 + h3 * h3;
    }
#pragma unroll
    for (int m = 1; m < 64; m <<= 1) {
      S += __shfl_xor(S, m);
      Q += __shfl_xor(Q, m);
    }
    if ((t & 63) == 0) { sredS[t >> 6] = S; sredQ[t >> 6] = Q; }
  }
  __syncthreads();
  if (t < 8) {
    atomicAdd(&sums[c0 + t], sredS[t * 2] + sredS[t * 2 + 1]);
  } else if (t < 16) {
    int c = t - 8;
    atomicAdd(&sums[64 + c0 + c], sredQ[c * 2] + sredQ[c * 2 + 1]);
  }
}

// ---------- per-graph fused: BN+ReLU+score -> topk -> pool+readout -> remap+deg ----------
__global__ __launch_bounds__(512) void post_kernel(
    const float* __restrict__ hT, const float* __restrict__ sums,
    const float* __restrict__ gamma, const float* __restrict__ beta,
    const float* __restrict__ p, float* __restrict__ xpoolT,
    uint32_t* __restrict__ packed, float* __restrict__ dinv_g,
    float* __restrict__ readout,
    const float* __restrict__ Wm, const float* __restrict__ bm,
    float* __restrict__ out,
    int npg, int k, float inv_n) {
  __shared__ float ssc[64], ssh[64], sp[64];
  __shared__ float invPn;
  __shared__ float __align__(16) sscore[1024];
  __shared__ float stanh[1024];
  __shared__ int slmap[1024];
  __shared__ int stmp[1024];
  __shared__ float srow[8][1024];
  __shared__ float redS[64], redM[64];
  __shared__ float fro[128];
  int b = blockIdx.x, t = threadIdx.x;
  int gbase = b * npg;
  size_t Nn = (size_t)npg * 128;
  if (t < 64) {
    float mu = sums[t] * inv_n;
    float var = fmaxf(sums[64 + t] * inv_n - mu * mu, 0.0f);
    float sc = rsqrtf(var + 1e-5f) * gamma[t];
    ssc[t] = sc; ssh[t] = beta[t] - mu * sc; sp[t] = p[t];
  }
  for (int i = t; i < 1024; i += 512) sscore[i] = -INFINITY;
  __syncthreads();
  if (t == 0) {
    float s = 0.0f;
    for (int i = 0; i < 64; i++) s += sp[i] * sp[i];
    invPn = rsqrtf(s);
  }
  __syncthreads();
  // ---- pass A: per-node score, coalesced channel-row loads ----
  {
    bool has2 = (t + 512) < npg;
    float s0 = 0.0f, s1 = 0.0f;
    const float* hp = hT + gbase;
    for (int c = 0; c < 64; c++) {
      float sc = ssc[c], sh = ssh[c], pc = sp[c];
      float v0 = hp[t];
      float y0 = fmaxf(fmaf(v0, sc, sh), 0.0f);
      s0 = fmaf(y0, pc, s0);
      if (has2) {
        float v1 = hp[t + 512];
        float y1 = fmaxf(fmaf(v1, sc, sh), 0.0f);
        s1 = fmaf(y1, pc, s1);
      }
      hp += Nn;
    }
    float ipn = invPn;
    float sc0 = s0 * ipn;
    sscore[t] = sc0;
    stanh[t] = tanhf(sc0);
    if (has2) {
      float sc1 = s1 * ipn;
      sscore[t + 512] = sc1;
      stanh[t + 512] = tanhf(sc1);
    }
  }
  __syncthreads();
  // ---- topk: rank counting, 2 slots/thread over padded 1024 ----
  {
    float my[2]; int rk[2];
#pragma unroll
    for (int m = 0; m < 2; m++) { my[m] = sscore[t * 2 + m]; rk[m] = 0; }
    for (int jb = 0; jb < 256; jb++) {
      float4 v = ((const float4*)sscore)[jb];
      int j0 = jb * 4;
#pragma unroll
      for (int m = 0; m < 2; m++) {
        int gi = t * 2 + m;
        rk[m] += (v.x > my[m]) || (v.x == my[m] && (j0 + 0) < gi);
        rk[m] += (v.y > my[m]) || (v.y == my[m] && (j0 + 1) < gi);
        rk[m] += (v.z > my[m]) || (v.z == my[m] && (j0 + 2) < gi);
        rk[m] += (v.w > my[m]) || (v.w == my[m] && (j0 + 3) < gi);
      }
    }
#pragma unroll
    for (int m = 0; m < 2; m++) {
      int i = t * 2 + m;
      bool sel = (i < npg) && (rk[m] < k);
      slmap[i] = sel ? rk[m] : -1;
      if (sel) stmp[rk[m]] = i;
    }
  }
  __syncthreads();
  // ---- pass B: wave-per-channel; LDS row stage + gather; coalesced xpool stores ----
  {
    int w = t >> 6, lane = t & 63;
    int npg4 = npg >> 2;
    size_t Nk = (size_t)k * 128;
#pragma unroll
    for (int i = 0; i < 8; i++) {
      int c = w * 8 + i;
      const float* hrow = hT + (size_t)c * Nn + gbase;
      for (int p4 = lane; p4 < npg4; p4 += 64)
        *(float4*)(&srow[w][p4 * 4]) = *(const float4*)(hrow + p4 * 4);
      float scc = ssc[c], shh = ssh[c];
      float* xo = xpoolT ? (xpoolT + (size_t)c * Nk + (size_t)b * k) : nullptr;
      float S = 0.0f, M = -INFINITY;
      for (int r = lane; r < k; r += 64) {
        int old = stmp[r];
        float y = fmaxf(fmaf(srow[w][old], scc, shh), 0.0f) * stanh[old];
        if (xo) xo[r] = y;
        S += y; M = fmaxf(M, y);
      }
#pragma unroll
      for (int m = 1; m < 64; m <<= 1) {
        S += __shfl_xor(S, m);
        M = fmaxf(M, __shfl_xor(M, m));
      }
      if (lane == 0) { redS[c] = S; redM[c] = M; }
    }
  }
  __syncthreads();
  if (t < 64) {
    float mean = redS[t] / (float)k;
    float Mg = redM[t];
    float* ro = readout + (size_t)b * 128;
    if (out == nullptr) {
      ro[t] += mean;
      ro[64 + t] += Mg;
    } else {
      fro[t] = ro[t] + mean;
      fro[64 + t] = ro[64 + t] + Mg;
    }
  }
  __syncthreads();
  if (out != nullptr && t < 10) {
    float acc = bm[t];
    for (int c = 0; c < 128; c++) acc = fmaf(fro[c], Wm[c * 10 + t], acc);
    out[b * 10 + t] = acc;
  }
  // ---- pass C: remap edges + new degree + dinv for next layer ----
  if (xpoolT != nullptr) {
    for (int i = t; i < 1024; i += 512) stmp[i] = 0;
    __syncthreads();
    uint32_t* pe = packed + (size_t)b * EPG;
    for (int e = t; e < EPG; e += 512) {
      uint32_t pk = pe[e];
      uint32_t outpk = 0;
      if (pk & VALID) {
        int ns = slmap[pk & 1023], nd = slmap[(pk >> 10) & 1023];
        if (ns >= 0 && nd >= 0) {
          outpk = (uint32_t)ns | ((uint32_t)nd << 10) | VALID;
          atomicAdd(&stmp[nd], 1);
        }
      }
      pe[e] = outpk;
    }
    __syncthreads();
    for (int r = t; r < k; r += 512)
      dinv_g[(size_t)b * k + r] = rsqrtf((float)stmp[r] + 1.0f);
  }
}

extern "C" void kernel_launch(void* const* d_in, const int* in_sizes, int n_in,
                              void* d_out, int out_size, void* d_ws, size_t ws_size,
                              hipStream_t stream) {
  (void)in_sizes; (void)n_in; (void)out_size; (void)ws_size;
  const float* x  = (const float*)d_in[0];
  const int*   ei = (const int*)d_in[1];
  const float* Wk[3]  = {(const float*)d_in[2],  (const float*)d_in[7],  (const float*)d_in[12]};
  const float* bk[3]  = {(const float*)d_in[3],  (const float*)d_in[8],  (const float*)d_in[13]};
  const float* gk[3]  = {(const float*)d_in[4],  (const float*)d_in[9],  (const float*)d_in[14]};
  const float* btk[3] = {(const float*)d_in[5],  (const float*)d_in[10], (const float*)d_in[15]};
  const float* pk[3]  = {(const float*)d_in[6],  (const float*)d_in[11], (const float*)d_in[16]};
  const float* Wm = (const float*)d_in[17];
  const float* bm = (const float*)d_in[18];
  float* out = (float*)d_out;

  // ---- workspace carve (floats); all feature buffers channel-major [64][N] ----
  float* ws = (float*)d_ws;
  size_t off = 0;
  auto alloc = [&](size_t nfl) {
    float* ptr = ws + off;
    off += (nfl + 63) & ~(size_t)63;
    return ptr;
  };
  float* bufXW = alloc((size_t)131072 * 64);   // xw^T
  float* bufH  = alloc((size_t)131072 * 64);   // h^T
  float* bufP  = alloc((size_t)104960 * 64);   // xpool^T
  float* dinv_g = alloc(131072);
  uint32_t* packed = (uint32_t*)alloc(EDGES);
  float* sums3 = alloc(3 * 128);
  float* readout = alloc(NGR * 2 * HID);

  pack_init<<<NGR, 256, 0, stream>>>(ei, packed, dinv_g, sums3, readout);

  // =============== Block 1: n=1024 -> k=820 ===============
  {
    const int npg = 1024, k = 820, Nc = NGR * npg;
    gemm_xw<128, false><<<Nc / 128, 256, 0, stream>>>(x, Wk[0], bufXW, Nc);
    edge_agg<<<8 * NGR, 1024, 0, stream>>>(packed, dinv_g, bufXW, bk[0], bufH,
                                           sums3, npg);
    post_kernel<<<NGR, 512, 0, stream>>>(bufH, sums3, gk[0], btk[0], pk[0],
                                         bufP, packed, dinv_g, readout,
                                         nullptr, nullptr, nullptr,
                                         npg, k, 1.0f / Nc);
  }
  // =============== Block 2: n=820 -> k=656 ===============
  {
    const int npg = 820, k = 656, Nc = NGR * npg;
    gemm_xw<64, true><<<Nc / 128, 256, 0, stream>>>(bufP, Wk[1], bufXW, Nc);
    edge_agg<<<8 * NGR, 1024, 0, stream>>>(packed, dinv_g, bufXW, bk[1], bufH,
                                           sums3 + 128, npg);
    post_kernel<<<NGR, 512, 0, stream>>>(bufH, sums3 + 128, gk[1], btk[1], pk[1],
                                         bufP, packed, dinv_g, readout,
                                         nullptr, nullptr, nullptr,
                                         npg, k, 1.0f / Nc);
  }
  // =============== Block 3: n=656 -> k=525 ===============
  {
    const int npg = 656, k = 525, Nc = NGR * npg;
    gemm_xw<64, true><<<Nc / 128, 256, 0, stream>>>(bufP, Wk[2], bufXW, Nc);
    edge_agg<<<8 * NGR, 1024, 0, stream>>>(packed, dinv_g, bufXW, bk[2], bufH,
                                           sums3 + 256, npg);
    post_kernel<<<NGR, 512, 0, stream>>>(bufH, sums3 + 256, gk[2], btk[2], pk[2],
                                         nullptr, packed, dinv_g, readout,
                                         Wm, bm, out,
                                         npg, k, 1.0f / Nc);
  }
}

// Round 5
// 599.447 us; speedup vs baseline: 2.6333x; 2.0155x over previous
//
#include <hip/hip_runtime.h>
#include <cmath>
#include <cstdint>
#include <cstddef>

#define HID 64
#define NGR 128            // B graphs
#define NTOT 131072        // 128 * 1024 nodes, fixed index space all layers
#define EDGES 1048576      // B * 1024 * 8
#define EPG 8192           // edges per graph

// ---------- once: pack edges, degree hist, CSR (rowstart + u16 src lists), dinv ----------
__global__ __launch_bounds__(256) void pack_init(
    const int* __restrict__ ei, uint32_t* __restrict__ packed,
    uint16_t* __restrict__ csr_g, uint32_t* __restrict__ rs_g,
    float* __restrict__ dinv_g, float* __restrict__ sums3,
    float* __restrict__ readout) {
  __shared__ int hist[1024];
  __shared__ int part[256];
  __shared__ int cursor[1024];
  int b = blockIdx.x, t = threadIdx.x;
  for (int i = t; i < 1024; i += 256) hist[i] = 0;
  __syncthreads();
  int ebase = b * EPG, nbase = b << 10;
  for (int e = t; e < EPG; e += 256) {
    uint32_t s = (uint32_t)(ei[ebase + e] - nbase);
    uint32_t d = (uint32_t)(ei[EDGES + ebase + e] - nbase);
    packed[ebase + e] = s | (d << 10);
    atomicAdd(&hist[(int)d], 1);
  }
  __syncthreads();
  int h0 = hist[t * 4], h1 = hist[t * 4 + 1], h2 = hist[t * 4 + 2], h3 = hist[t * 4 + 3];
  int tot = h0 + h1 + h2 + h3;
  part[t] = tot;
  __syncthreads();
  // Kogge-Stone inclusive scan over 256 partials
  for (int off = 1; off < 256; off <<= 1) {
    int v = (t >= off) ? part[t - off] : 0;
    __syncthreads();
    part[t] += v;
    __syncthreads();
  }
  int excl = part[t] - tot;
  int r0 = excl, r1 = r0 + h0, r2 = r1 + h1, r3 = r2 + h2;
  cursor[t * 4 + 0] = r0; cursor[t * 4 + 1] = r1;
  cursor[t * 4 + 2] = r2; cursor[t * 4 + 3] = r3;
  uint32_t* rg = rs_g + b * 1025;
  rg[t * 4 + 0] = r0; rg[t * 4 + 1] = r1; rg[t * 4 + 2] = r2; rg[t * 4 + 3] = r3;
  if (t == 255) rg[1024] = EPG;
  for (int i = t; i < 1024; i += 256)
    dinv_g[(b << 10) + i] = rsqrtf((float)hist[i] + 1.0f);
  __syncthreads();
  // scatter src ids into dst-sorted CSR
  for (int e = t; e < EPG; e += 256) {
    uint32_t pk = packed[ebase + e];
    int d = (pk >> 10) & 1023;
    int idx = atomicAdd(&cursor[d], 1);
    csr_g[ebase + idx] = (uint16_t)(pk & 1023);
  }
  if (b < 3 && t < 128) sums3[b * 128 + t] = 0.0f;
  if (t < 128) readout[b * 128 + t] = 0.0f;
}

// ---------- xw^T = (X @ W)^T.  X row-major [N,DIN] (TIN=0) or channel-major [DIN,N] (TIN=1).
template<int DIN, bool TIN>
__global__ __launch_bounds__(256) void gemm_xw(
    const float* __restrict__ X, const float* __restrict__ W,
    float* __restrict__ XWT, int n_nodes) {
  __shared__ float sW[32 * HID];       // 8 KB
  __shared__ float sX[32 * 132];       // 16.5 KB  (k-major, node inner, pad 4)
  const int t = threadIdx.x;
  const int cq = t & 15, ng = t >> 4;
  const int c4 = cq * 4;
  const int node0 = blockIdx.x * 128;
  const size_t Nn = (size_t)n_nodes;
  float acc[8][4];
#pragma unroll
  for (int n = 0; n < 8; n++) { acc[n][0]=0.f; acc[n][1]=0.f; acc[n][2]=0.f; acc[n][3]=0.f; }

  for (int k0 = 0; k0 < DIN; k0 += 32) {
    ((float4*)sW)[t * 2 + 0] = ((const float4*)(W + (size_t)k0 * HID))[t * 2 + 0];
    ((float4*)sW)[t * 2 + 1] = ((const float4*)(W + (size_t)k0 * HID))[t * 2 + 1];
    if (TIN) {
#pragma unroll
      for (int it = 0; it < 4; it++) {
        int slot = t + it * 256;
        int row = slot >> 5, col4 = (slot & 31) * 4;
        *(float4*)(sX + row * 132 + col4) =
            *(const float4*)(X + (size_t)(k0 + row) * Nn + node0 + col4);
      }
    } else {
      int i4 = (t & 7) * 4;
      int nl = t >> 3;
#pragma unroll
      for (int rep = 0; rep < 4; rep++) {
        int nn = nl + rep * 32;
        float4 v = *(const float4*)(X + (size_t)(node0 + nn) * DIN + k0 + i4);
        sX[(i4 + 0) * 132 + nn] = v.x;
        sX[(i4 + 1) * 132 + nn] = v.y;
        sX[(i4 + 2) * 132 + nn] = v.z;
        sX[(i4 + 3) * 132 + nn] = v.w;
      }
    }
    __syncthreads();
#pragma unroll 4
    for (int i = 0; i < 32; i++) {
      float4 w = *(const float4*)(sW + i * HID + c4);
      const float* xr = sX + i * 132 + ng * 8;
      float4 xa = *(const float4*)xr;
      float4 xb = *(const float4*)(xr + 4);
      float xn[8] = {xa.x, xa.y, xa.z, xa.w, xb.x, xb.y, xb.z, xb.w};
#pragma unroll
      for (int n = 0; n < 8; n++) {
        acc[n][0] = fmaf(xn[n], w.x, acc[n][0]);
        acc[n][1] = fmaf(xn[n], w.y, acc[n][1]);
        acc[n][2] = fmaf(xn[n], w.z, acc[n][2]);
        acc[n][3] = fmaf(xn[n], w.w, acc[n][3]);
      }
    }
    __syncthreads();
  }
#pragma unroll
  for (int cc = 0; cc < 4; cc++) {
    int row = c4 + cc;
    float* o = XWT + (size_t)row * Nn + node0 + ng * 8;
    *(float4*)(o + 0) = make_float4(acc[0][cc], acc[1][cc], acc[2][cc], acc[3][cc]);
    *(float4*)(o + 4) = make_float4(acc[4][cc], acc[5][cc], acc[6][cc], acc[7][cc]);
  }
}

// ---------- CSR aggregate (no atomics) + self-loop + bias + masked BN sums ----------
// blockIdx = q*128 + g ; 1024 thr = 128 dst-groups x 8 channels; LDS ~57 KB -> 2 blocks/CU
__global__ __launch_bounds__(1024, 8) void edge_agg(
    const uint16_t* __restrict__ csr_g, const uint32_t* __restrict__ rs_g,
    const float* __restrict__ dinv_g, const float* __restrict__ xwT,
    const float* __restrict__ bias, float* __restrict__ hT,
    float* __restrict__ sums) {
  __shared__ float xws[8 * 1028];      // prescaled xw*dinv; stride 1028: 8ch -> 8 banks
  __shared__ float dv[1024];
  __shared__ uint32_t rs[1025];
  __shared__ uint16_t csr_s[8192];
  __shared__ float sredS[16][8], sredQ[16][8];
  const int g = blockIdx.x & 127;
  const int q = blockIdx.x >> 7;
  const int c0 = q * 8;
  const int t = threadIdx.x;
  const int gbase = g << 10;

  dv[t] = dinv_g[gbase + t];
  if (t < 1024) rs[t] = rs_g[g * 1025 + t];
  if (t == 0) rs[1024] = EPG;
  ((uint4*)csr_s)[t] = ((const uint4*)(csr_g + (size_t)g * EPG))[t];
  for (int slot = t; slot < 2048; slot += 1024) {
    int c = slot >> 8, pos4 = (slot & 255) * 4;
    float4 v = *(const float4*)(xwT + (size_t)(c0 + c) * NTOT + gbase + pos4);
    float4 dd = *(const float4*)(dinv_g + gbase + pos4);
    v.x *= dd.x; v.y *= dd.y; v.z *= dd.z; v.w *= dd.w;
    *(float4*)(xws + c * 1028 + pos4) = v;
  }
  __syncthreads();

  const int c = t & 7, j = t >> 3;
  const float* xc = xws + c * 1028;
  const float bv = bias[c0 + c];
  float* hrow = hT + (size_t)(c0 + c) * NTOT + gbase;
  float S = 0.0f, Q = 0.0f;
  for (int d = j; d < 1024; d += 128) {
    float dvd = dv[d];
    if (dvd == 0.0f) continue;             // dropped dst: skip whole row
    int e = rs[d], e1 = rs[d + 1];
    float a0 = 0.0f, a1 = 0.0f;
    for (; e + 2 <= e1; e += 2) {          // 2 independent chains; dropped src reads 0
      int s0 = csr_s[e], s1 = csr_s[e + 1];
      a0 += xc[s0];
      a1 += xc[s1];
    }
    if (e < e1) a0 += xc[csr_s[e]];
    float hv = (a0 + a1 + xc[d]) * dvd + bv;
    hrow[d] = hv;
    S += hv; Q += hv * hv;
  }
#pragma unroll
  for (int m = 8; m < 64; m <<= 1) { S += __shfl_xor(S, m); Q += __shfl_xor(Q, m); }
  {
    int lane = t & 63, w = t >> 6;
    if (lane < 8) { sredS[w][lane] = S; sredQ[w][lane] = Q; }
  }
  __syncthreads();
  if (t < 8) {
    float a = 0.0f;
    for (int w2 = 0; w2 < 16; w2++) a += sredS[w2][t];
    atomicAdd(&sums[c0 + t], a);
  } else if (t < 16) {
    int cc = t - 8;
    float a = 0.0f;
    for (int w2 = 0; w2 < 16; w2++) a += sredQ[w2][cc];
    atomicAdd(&sums[64 + cc + c0], a);
  }
}

// ---------- per-graph fused: BN+ReLU+score -> topk(mask) -> masked pool+readout -> next deg ----------
__global__ __launch_bounds__(512) void post_kernel(
    const float* __restrict__ hT, const float* __restrict__ sums,
    const float* __restrict__ gamma, const float* __restrict__ beta,
    const float* __restrict__ p, float* __restrict__ xT_out,
    const uint32_t* __restrict__ packed, float* __restrict__ dinv_g,
    float* __restrict__ readout, const float* __restrict__ Wm,
    const float* __restrict__ bm, float* __restrict__ out,
    int k, float inv_n) {
  __shared__ float ssc[64], ssh[64], sp[64];
  __shared__ float invPn;
  __shared__ float __align__(16) sscore[1024];
  __shared__ float stanh[1024];
  __shared__ int snext[1024];
  __shared__ int shist[1024];
  __shared__ float redS[64], redM[64];
  __shared__ float fro[128];
  int b = blockIdx.x, t = threadIdx.x;
  int gbase = b << 10;
  if (t < 64) {
    float mu = sums[t] * inv_n;
    float var = fmaxf(sums[64 + t] * inv_n - mu * mu, 0.0f);
    float sc = rsqrtf(var + 1e-5f) * gamma[t];
    ssc[t] = sc; ssh[t] = beta[t] - mu * sc; sp[t] = p[t];
  }
  __syncthreads();
  if (t == 0) {
    float s = 0.0f;
    for (int i = 0; i < 64; i++) s += sp[i] * sp[i];
    invPn = rsqrtf(s);
  }
  __syncthreads();
  // ---- pass A: scores (coalesced channel-row loads); dropped -> -inf ----
  {
    float s0 = 0.0f, s1 = 0.0f;
    const float* hp = hT + gbase;
    for (int cch = 0; cch < 64; cch++) {
      float sc = ssc[cch], sh = ssh[cch], pc = sp[cch];
      float y0 = fmaxf(fmaf(hp[t], sc, sh), 0.0f);
      float y1 = fmaxf(fmaf(hp[t + 512], sc, sh), 0.0f);
      s0 = fmaf(y0, pc, s0);
      s1 = fmaf(y1, pc, s1);
      hp += NTOT;
    }
    bool k0 = dinv_g[gbase + t] > 0.0f;
    bool k1 = dinv_g[gbase + t + 512] > 0.0f;
    float ipn = invPn;
    float v0 = s0 * ipn, v1 = s1 * ipn;
    sscore[t] = k0 ? v0 : -INFINITY;
    sscore[t + 512] = k1 ? v1 : -INFINITY;
    stanh[t] = tanhf(v0);
    stanh[t + 512] = tanhf(v1);
  }
  __syncthreads();
  // ---- topk: rank counting over fixed 1024 slots -> kept mask ----
  {
    float my0 = sscore[t * 2], my1 = sscore[t * 2 + 1];
    int r0 = 0, r1 = 0;
    int g0 = t * 2, g1 = t * 2 + 1;
    for (int jb = 0; jb < 256; jb++) {
      float4 v = ((const float4*)sscore)[jb];
      int j0 = jb * 4;
      r0 += (v.x > my0) || (v.x == my0 && (j0 + 0) < g0);
      r0 += (v.y > my0) || (v.y == my0 && (j0 + 1) < g0);
      r0 += (v.z > my0) || (v.z == my0 && (j0 + 2) < g0);
      r0 += (v.w > my0) || (v.w == my0 && (j0 + 3) < g0);
      r1 += (v.x > my1) || (v.x == my1 && (j0 + 0) < g1);
      r1 += (v.y > my1) || (v.y == my1 && (j0 + 1) < g1);
      r1 += (v.z > my1) || (v.z == my1 && (j0 + 2) < g1);
      r1 += (v.w > my1) || (v.w == my1 && (j0 + 3) < g1);
    }
    snext[g0] = (r0 < k) ? 1 : 0;
    snext[g1] = (r1 < k) ? 1 : 0;
  }
  __syncthreads();
  // ---- pass B: linear masked pool; x_next = kept ? y*tanh : 0 ; mean/max over kept ----
  {
    int w = t >> 6, lane = t & 63;
#pragma unroll
    for (int i = 0; i < 8; i++) {
      int cch = w * 8 + i;
      const float* hrow = hT + (size_t)cch * NTOT + gbase;
      float* xrow = xT_out ? (xT_out + (size_t)cch * NTOT + gbase) : nullptr;
      float scc = ssc[cch], shh = ssh[cch];
      float S = 0.0f, M = -INFINITY;
      for (int nd = lane; nd < 1024; nd += 64) {
        bool kn = snext[nd] != 0;
        float y = fmaxf(fmaf(hrow[nd], scc, shh), 0.0f) * stanh[nd];
        y = kn ? y : 0.0f;
        if (xrow) xrow[nd] = y;
        S += y;
        if (kn) M = fmaxf(M, y);
      }
#pragma unroll
      for (int m = 1; m < 64; m <<= 1) {
        S += __shfl_xor(S, m);
        M = fmaxf(M, __shfl_xor(M, m));
      }
      if (lane == 0) { redS[cch] = S; redM[cch] = M; }
    }
  }
  __syncthreads();
  if (t < 64) {
    float mean = redS[t] / (float)k;
    float Mg = redM[t];
    float* ro = readout + (size_t)b * 128;
    if (out == nullptr) {
      ro[t] += mean;
      ro[64 + t] += Mg;
    } else {
      fro[t] = ro[t] + mean;
      fro[64 + t] = ro[64 + t] + Mg;
    }
  }
  __syncthreads();
  if (out != nullptr && t < 10) {
    float acc = bm[t];
    for (int cc = 0; cc < 128; cc++) acc = fmaf(fro[cc], Wm[cc * 10 + t], acc);
    out[b * 10 + t] = acc;
  }
  // ---- pass C: next-layer degree/dinv from static edges + kept mask ----
  if (xT_out != nullptr) {
    for (int i = t; i < 1024; i += 512) shist[i] = 0;
    __syncthreads();
    const uint32_t* pe = packed + (size_t)b * EPG;
    for (int e = t; e < EPG; e += 512) {
      uint32_t pk = pe[e];
      int s = pk & 1023, d = (pk >> 10) & 1023;
      if (snext[s] && snext[d]) atomicAdd(&shist[d], 1);
    }
    __syncthreads();
    for (int i = t; i < 1024; i += 512)
      dinv_g[gbase + i] = snext[i] ? rsqrtf((float)shist[i] + 1.0f) : 0.0f;
  }
}

extern "C" void kernel_launch(void* const* d_in, const int* in_sizes, int n_in,
                              void* d_out, int out_size, void* d_ws, size_t ws_size,
                              hipStream_t stream) {
  (void)in_sizes; (void)n_in; (void)out_size; (void)ws_size;
  const float* x  = (const float*)d_in[0];
  const int*   ei = (const int*)d_in[1];
  const float* Wk[3]  = {(const float*)d_in[2],  (const float*)d_in[7],  (const float*)d_in[12]};
  const float* bk[3]  = {(const float*)d_in[3],  (const float*)d_in[8],  (const float*)d_in[13]};
  const float* gk[3]  = {(const float*)d_in[4],  (const float*)d_in[9],  (const float*)d_in[14]};
  const float* btk[3] = {(const float*)d_in[5],  (const float*)d_in[10], (const float*)d_in[15]};
  const float* pk[3]  = {(const float*)d_in[6],  (const float*)d_in[11], (const float*)d_in[16]};
  const float* Wm = (const float*)d_in[17];
  const float* bm = (const float*)d_in[18];
  float* out = (float*)d_out;

  // ---- workspace carve (float units); feature buffers channel-major [64][NTOT] ----
  float* ws = (float*)d_ws;
  size_t off = 0;
  auto alloc = [&](size_t nfl) {
    float* ptr = ws + off;
    off += (nfl + 63) & ~(size_t)63;
    return ptr;
  };
  float* bufXW = alloc((size_t)NTOT * 64);
  float* bufH  = alloc((size_t)NTOT * 64);
  float* bufX  = alloc((size_t)NTOT * 64);
  float* dinv_g = alloc(NTOT);
  uint32_t* packed = (uint32_t*)alloc(EDGES);
  uint16_t* csr    = (uint16_t*)alloc(EDGES / 2);
  uint32_t* rs     = (uint32_t*)alloc(NGR * 1025);
  float* sums3 = alloc(3 * 128);
  float* readout = alloc(NGR * 2 * HID);

  pack_init<<<NGR, 256, 0, stream>>>(ei, packed, csr, rs, dinv_g, sums3, readout);

  // =============== Layer 1: kept 1024 -> k=820 ===============
  gemm_xw<128, false><<<NTOT / 128, 256, 0, stream>>>(x, Wk[0], bufXW, NTOT);
  edge_agg<<<8 * NGR, 1024, 0, stream>>>(csr, rs, dinv_g, bufXW, bk[0], bufH, sums3);
  post_kernel<<<NGR, 512, 0, stream>>>(bufH, sums3, gk[0], btk[0], pk[0],
                                       bufX, packed, dinv_g, readout,
                                       nullptr, nullptr, nullptr,
                                       820, 1.0f / (float)NTOT);
  // =============== Layer 2: kept 820 -> k=656 ===============
  gemm_xw<64, true><<<NTOT / 128, 256, 0, stream>>>(bufX, Wk[1], bufXW, NTOT);
  edge_agg<<<8 * NGR, 1024, 0, stream>>>(csr, rs, dinv_g, bufXW, bk[1], bufH, sums3 + 128);
  post_kernel<<<NGR, 512, 0, stream>>>(bufH, sums3 + 128, gk[1], btk[1], pk[1],
                                       bufX, packed, dinv_g, readout,
                                       nullptr, nullptr, nullptr,
                                       656, 1.0f / (float)(NGR * 820));
  // =============== Layer 3: kept 656 -> k=525 ===============
  gemm_xw<64, true><<<NTOT / 128, 256, 0, stream>>>(bufX, Wk[2], bufXW, NTOT);
  edge_agg<<<8 * NGR, 1024, 0, stream>>>(csr, rs, dinv_g, bufXW, bk[2], bufH, sums3 + 256);
  post_kernel<<<NGR, 512, 0, stream>>>(bufH, sums3 + 256, gk[2], btk[2], pk[2],
                                       nullptr, packed, dinv_g, readout,
                                       Wm, bm, out,
                                       525, 1.0f / (float)(NGR * 656));
}

// Round 6
// 528.961 us; speedup vs baseline: 2.9842x; 1.1333x over previous
//
#include <hip/hip_runtime.h>
#include <cmath>
#include <cstdint>
#include <cstddef>

#define HID 64
#define NGR 128            // B graphs
#define NTOT 131072        // 128 * 1024 nodes, fixed index space all layers
#define EDGES 1048576      // B * 1024 * 8
#define EPG 8192           // edges per graph

// ---------- once: pack edges, degree hist, CSR (rowstart + u16 src lists), dinv ----------
__global__ __launch_bounds__(256) void pack_init(
    const int* __restrict__ ei, uint32_t* __restrict__ packed,
    uint16_t* __restrict__ csr_g, uint32_t* __restrict__ rs_g,
    float* __restrict__ dinv_g, float* __restrict__ sums3,
    float* __restrict__ readout) {
  __shared__ int hist[1024];
  __shared__ int part[256];
  __shared__ int cursor[1024];
  int b = blockIdx.x, t = threadIdx.x;
  for (int i = t; i < 1024; i += 256) hist[i] = 0;
  __syncthreads();
  int ebase = b * EPG, nbase = b << 10;
  for (int e = t; e < EPG; e += 256) {
    uint32_t s = (uint32_t)(ei[ebase + e] - nbase);
    uint32_t d = (uint32_t)(ei[EDGES + ebase + e] - nbase);
    packed[ebase + e] = s | (d << 10);
    atomicAdd(&hist[(int)d], 1);
  }
  __syncthreads();
  int h0 = hist[t * 4], h1 = hist[t * 4 + 1], h2 = hist[t * 4 + 2], h3 = hist[t * 4 + 3];
  int tot = h0 + h1 + h2 + h3;
  part[t] = tot;
  __syncthreads();
  for (int off = 1; off < 256; off <<= 1) {
    int v = (t >= off) ? part[t - off] : 0;
    __syncthreads();
    part[t] += v;
    __syncthreads();
  }
  int excl = part[t] - tot;
  int r0 = excl, r1 = r0 + h0, r2 = r1 + h1, r3 = r2 + h2;
  cursor[t * 4 + 0] = r0; cursor[t * 4 + 1] = r1;
  cursor[t * 4 + 2] = r2; cursor[t * 4 + 3] = r3;
  uint32_t* rg = rs_g + b * 1025;
  rg[t * 4 + 0] = r0; rg[t * 4 + 1] = r1; rg[t * 4 + 2] = r2; rg[t * 4 + 3] = r3;
  if (t == 255) rg[1024] = EPG;
  for (int i = t; i < 1024; i += 256)
    dinv_g[(b << 10) + i] = rsqrtf((float)hist[i] + 1.0f);
  __syncthreads();
  for (int e = t; e < EPG; e += 256) {
    uint32_t pk = packed[ebase + e];
    int d = (pk >> 10) & 1023;
    int idx = atomicAdd(&cursor[d], 1);
    csr_g[ebase + idx] = (uint16_t)(pk & 1023);
  }
  if (b < 3 && t < 128) sums3[b * 128 + t] = 0.0f;
  if (t < 128) readout[b * 128 + t] = 0.0f;
}

// ---------- xw^T = (X @ W)^T.  X row-major [N,DIN] (TIN=0) or channel-major [DIN,N] (TIN=1).
template<int DIN, bool TIN>
__global__ __launch_bounds__(256) void gemm_xw(
    const float* __restrict__ X, const float* __restrict__ W,
    float* __restrict__ XWT, int n_nodes) {
  __shared__ float sW[32 * HID];       // 8 KB
  __shared__ float sX[32 * 132];       // 16.5 KB  (k-major, node inner, pad 4)
  const int t = threadIdx.x;
  const int cq = t & 15, ng = t >> 4;
  const int c4 = cq * 4;
  const int node0 = blockIdx.x * 128;
  const size_t Nn = (size_t)n_nodes;
  float acc[8][4];
#pragma unroll
  for (int n = 0; n < 8; n++) { acc[n][0]=0.f; acc[n][1]=0.f; acc[n][2]=0.f; acc[n][3]=0.f; }

  for (int k0 = 0; k0 < DIN; k0 += 32) {
    ((float4*)sW)[t * 2 + 0] = ((const float4*)(W + (size_t)k0 * HID))[t * 2 + 0];
    ((float4*)sW)[t * 2 + 1] = ((const float4*)(W + (size_t)k0 * HID))[t * 2 + 1];
    if (TIN) {
#pragma unroll
      for (int it = 0; it < 4; it++) {
        int slot = t + it * 256;
        int row = slot >> 5, col4 = (slot & 31) * 4;
        *(float4*)(sX + row * 132 + col4) =
            *(const float4*)(X + (size_t)(k0 + row) * Nn + node0 + col4);
      }
    } else {
      int i4 = (t & 7) * 4;
      int nl = t >> 3;
#pragma unroll
      for (int rep = 0; rep < 4; rep++) {
        int nn = nl + rep * 32;
        float4 v = *(const float4*)(X + (size_t)(node0 + nn) * DIN + k0 + i4);
        sX[(i4 + 0) * 132 + nn] = v.x;
        sX[(i4 + 1) * 132 + nn] = v.y;
        sX[(i4 + 2) * 132 + nn] = v.z;
        sX[(i4 + 3) * 132 + nn] = v.w;
      }
    }
    __syncthreads();
#pragma unroll 4
    for (int i = 0; i < 32; i++) {
      float4 w = *(const float4*)(sW + i * HID + c4);
      const float* xr = sX + i * 132 + ng * 8;
      float4 xa = *(const float4*)xr;
      float4 xb = *(const float4*)(xr + 4);
      float xn[8] = {xa.x, xa.y, xa.z, xa.w, xb.x, xb.y, xb.z, xb.w};
#pragma unroll
      for (int n = 0; n < 8; n++) {
        acc[n][0] = fmaf(xn[n], w.x, acc[n][0]);
        acc[n][1] = fmaf(xn[n], w.y, acc[n][1]);
        acc[n][2] = fmaf(xn[n], w.z, acc[n][2]);
        acc[n][3] = fmaf(xn[n], w.w, acc[n][3]);
      }
    }
    __syncthreads();
  }
#pragma unroll
  for (int cc = 0; cc < 4; cc++) {
    int row = c4 + cc;
    float* o = XWT + (size_t)row * Nn + node0 + ng * 8;
    *(float4*)(o + 0) = make_float4(acc[0][cc], acc[1][cc], acc[2][cc], acc[3][cc]);
    *(float4*)(o + 4) = make_float4(acc[4][cc], acc[5][cc], acc[6][cc], acc[7][cc]);
  }
}

// ---------- CSR aggregate (no atomics) + self-loop + bias + masked BN sums ----------
__global__ __launch_bounds__(1024, 8) void edge_agg(
    const uint16_t* __restrict__ csr_g, const uint32_t* __restrict__ rs_g,
    const float* __restrict__ dinv_g, const float* __restrict__ xwT,
    const float* __restrict__ bias, float* __restrict__ hT,
    float* __restrict__ sums) {
  __shared__ float xws[8 * 1028];      // prescaled xw*dinv; stride 1028: 8ch -> 8 banks
  __shared__ float dv[1024];
  __shared__ uint32_t rs[1025];
  __shared__ uint16_t csr_s[8192];
  __shared__ float sredS[16][8], sredQ[16][8];
  const int g = blockIdx.x & 127;
  const int q = blockIdx.x >> 7;
  const int c0 = q * 8;
  const int t = threadIdx.x;
  const int gbase = g << 10;

  dv[t] = dinv_g[gbase + t];
  if (t < 1024) rs[t] = rs_g[g * 1025 + t];
  if (t == 0) rs[1024] = EPG;
  ((uint4*)csr_s)[t] = ((const uint4*)(csr_g + (size_t)g * EPG))[t];
  for (int slot = t; slot < 2048; slot += 1024) {
    int c = slot >> 8, pos4 = (slot & 255) * 4;
    float4 v = *(const float4*)(xwT + (size_t)(c0 + c) * NTOT + gbase + pos4);
    float4 dd = *(const float4*)(dinv_g + gbase + pos4);
    v.x *= dd.x; v.y *= dd.y; v.z *= dd.z; v.w *= dd.w;
    *(float4*)(xws + c * 1028 + pos4) = v;
  }
  __syncthreads();

  const int c = t & 7, j = t >> 3;
  const float* xc = xws + c * 1028;
  const float bv = bias[c0 + c];
  float* hrow = hT + (size_t)(c0 + c) * NTOT + gbase;
  float S = 0.0f, Q = 0.0f;
  for (int d = j; d < 1024; d += 128) {
    float dvd = dv[d];
    if (dvd == 0.0f) continue;
    int e = rs[d], e1 = rs[d + 1];
    float a0 = 0.0f, a1 = 0.0f;
    for (; e + 2 <= e1; e += 2) {
      int s0 = csr_s[e], s1 = csr_s[e + 1];
      a0 += xc[s0];
      a1 += xc[s1];
    }
    if (e < e1) a0 += xc[csr_s[e]];
    float hv = (a0 + a1 + xc[d]) * dvd + bv;
    hrow[d] = hv;
    S += hv; Q += hv * hv;
  }
#pragma unroll
  for (int m = 8; m < 64; m <<= 1) { S += __shfl_xor(S, m); Q += __shfl_xor(Q, m); }
  {
    int lane = t & 63, w = t >> 6;
    if (lane < 8) { sredS[w][lane] = S; sredQ[w][lane] = Q; }
  }
  __syncthreads();
  if (t < 8) {
    float a = 0.0f;
    for (int w2 = 0; w2 < 16; w2++) a += sredS[w2][t];
    atomicAdd(&sums[c0 + t], a);
  } else if (t < 16) {
    int cc = t - 8;
    float a = 0.0f;
    for (int w2 = 0; w2 < 16; w2++) a += sredQ[w2][cc];
    atomicAdd(&sums[64 + cc + c0], a);
  }
}

// ---------- scores: BN+ReLU+dot(p) per node; grid = NGR*4 x 256 ----------
__global__ __launch_bounds__(256) void score_kernel(
    const float* __restrict__ hT, const float* __restrict__ sums,
    const float* __restrict__ gamma, const float* __restrict__ beta,
    const float* __restrict__ p, const float* __restrict__ dinv_g,
    float* __restrict__ score, float* __restrict__ stanh_g, float inv_n) {
  __shared__ float ssc[64], ssh[64], sp[64];
  __shared__ float sipn;
  int b = blockIdx.x >> 2, seg = (blockIdx.x & 3) << 8;
  int t = threadIdx.x;
  int node = (b << 10) + seg + t;
  if (t < 64) {
    float mu = sums[t] * inv_n;
    float var = fmaxf(sums[64 + t] * inv_n - mu * mu, 0.0f);
    float sc = rsqrtf(var + 1e-5f) * gamma[t];
    ssc[t] = sc; ssh[t] = beta[t] - mu * sc;
    sp[t] = p[t];
  }
  __syncthreads();
  if (t == 0) {
    float s = 0.0f;
    for (int i = 0; i < 64; i++) s += sp[i] * sp[i];
    sipn = rsqrtf(s);
  }
  __syncthreads();
  const float* hp = hT + node;
  float s0 = 0.0f;
#pragma unroll 16
  for (int c = 0; c < 64; c++) {
    float y = fmaxf(fmaf(hp[(size_t)c * NTOT], ssc[c], ssh[c]), 0.0f);
    s0 = fmaf(y, sp[c], s0);
  }
  float v0 = s0 * sipn;
  score[node] = (dinv_g[node] > 0.0f) ? v0 : -INFINITY;
  stanh_g[node] = tanhf(v0);
}

// ---------- per-graph topk (rank count) -> kept mask; fused next-layer dinv ----------
__global__ __launch_bounds__(1024) void topk_kernel(
    const float* __restrict__ score, const uint32_t* __restrict__ packed,
    float* __restrict__ dinv_g, int* __restrict__ snext_g, int k, int hasNext) {
  __shared__ float __align__(16) ssc[1024];
  __shared__ int snext[1024];
  __shared__ int shist[1024];
  int b = blockIdx.x, t = threadIdx.x;
  int gbase = b << 10;
  ssc[t] = score[gbase + t];
  shist[t] = 0;
  __syncthreads();
  float my = ssc[t];
  int r = 0;
  for (int jb = 0; jb < 256; jb++) {
    float4 v = ((const float4*)ssc)[jb];
    int j0 = jb * 4;
    r += (v.x > my) || (v.x == my && (j0 + 0) < t);
    r += (v.y > my) || (v.y == my && (j0 + 1) < t);
    r += (v.z > my) || (v.z == my && (j0 + 2) < t);
    r += (v.w > my) || (v.w == my && (j0 + 3) < t);
  }
  int kept = (r < k) ? 1 : 0;
  snext[t] = kept;
  snext_g[gbase + t] = kept;
  __syncthreads();
  if (hasNext) {
    const uint32_t* pe = packed + (size_t)b * EPG;
#pragma unroll
    for (int e0 = 0; e0 < EPG; e0 += 1024) {
      uint32_t pk = pe[e0 + t];
      int s = pk & 1023, d = (pk >> 10) & 1023;
      if (snext[s] & snext[d]) atomicAdd(&shist[d], 1);
    }
    __syncthreads();
    dinv_g[gbase + t] = kept ? rsqrtf((float)shist[t] + 1.0f) : 0.0f;
  }
}

// ---------- masked pool + readout accumulate; grid = 8*NGR x 256 ----------
__global__ __launch_bounds__(256) void pool_kernel(
    const float* __restrict__ hT, const float* __restrict__ sums,
    const float* __restrict__ gamma, const float* __restrict__ beta,
    const float* __restrict__ stanh_g, const int* __restrict__ snext_g,
    float* __restrict__ xT_out, float* __restrict__ readout,
    int k, float inv_n) {
  __shared__ float ssc[64], ssh[64];
  __shared__ float sth[1024];
  __shared__ int skn[1024];
  __shared__ float redS[4][8], redM[4][8];
  int g = blockIdx.x & 127, q = blockIdx.x >> 7;
  int t = threadIdx.x;
  int gbase = g << 10;
  if (t < 64) {
    float mu = sums[t] * inv_n;
    float var = fmaxf(sums[64 + t] * inv_n - mu * mu, 0.0f);
    float sc = rsqrtf(var + 1e-5f) * gamma[t];
    ssc[t] = sc; ssh[t] = beta[t] - mu * sc;
  }
  for (int i = t; i < 1024; i += 256) {
    sth[i] = stanh_g[gbase + i];
    skn[i] = snext_g[gbase + i];
  }
  __syncthreads();
  int lane = t & 63, w = t >> 6;
#pragma unroll
  for (int i = 0; i < 8; i++) {
    int c = q * 8 + i;
    const float* hrow = hT + (size_t)c * NTOT + gbase;
    float* xrow = xT_out ? (xT_out + (size_t)c * NTOT + gbase) : nullptr;
    float scc = ssc[c], shh = ssh[c];
    float S = 0.0f, M = -INFINITY;
    for (int nd = t; nd < 1024; nd += 256) {
      bool kn = skn[nd] != 0;
      float y = fmaxf(fmaf(hrow[nd], scc, shh), 0.0f) * sth[nd];
      y = kn ? y : 0.0f;
      if (xrow) xrow[nd] = y;
      S += y;
      if (kn) M = fmaxf(M, y);
    }
#pragma unroll
    for (int m = 1; m < 64; m <<= 1) {
      S += __shfl_xor(S, m);
      M = fmaxf(M, __shfl_xor(M, m));
    }
    if (lane == 0) { redS[w][i] = S; redM[w][i] = M; }
  }
  __syncthreads();
  if (t < 8) {
    float S = redS[0][t] + redS[1][t] + redS[2][t] + redS[3][t];
    readout[g * 128 + q * 8 + t] += S / (float)k;
  } else if (t < 16) {
    int i = t - 8;
    float M = fmaxf(fmaxf(redM[0][i], redM[1][i]), fmaxf(redM[2][i], redM[3][i]));
    readout[g * 128 + 64 + q * 8 + i] += M;
  }
}

// ---------------- out = readout @ Wm + bm ----------------
__global__ __launch_bounds__(256) void final_linear(
    const float* __restrict__ readout, const float* __restrict__ Wm,
    const float* __restrict__ bm, float* __restrict__ out) {
  int idx = blockIdx.x * 256 + threadIdx.x;
  if (idx >= NGR * 10) return;
  int b = idx / 10, o = idx - b * 10;
  float acc = bm[o];
  const float* r = readout + (size_t)b * 128;
  for (int c = 0; c < 128; c++) acc = fmaf(r[c], Wm[c * 10 + o], acc);
  out[idx] = acc;
}

extern "C" void kernel_launch(void* const* d_in, const int* in_sizes, int n_in,
                              void* d_out, int out_size, void* d_ws, size_t ws_size,
                              hipStream_t stream) {
  (void)in_sizes; (void)n_in; (void)out_size; (void)ws_size;
  const float* x  = (const float*)d_in[0];
  const int*   ei = (const int*)d_in[1];
  const float* Wk[3]  = {(const float*)d_in[2],  (const float*)d_in[7],  (const float*)d_in[12]};
  const float* bk[3]  = {(const float*)d_in[3],  (const float*)d_in[8],  (const float*)d_in[13]};
  const float* gk[3]  = {(const float*)d_in[4],  (const float*)d_in[9],  (const float*)d_in[14]};
  const float* btk[3] = {(const float*)d_in[5],  (const float*)d_in[10], (const float*)d_in[15]};
  const float* pk[3]  = {(const float*)d_in[6],  (const float*)d_in[11], (const float*)d_in[16]};
  const float* Wm = (const float*)d_in[17];
  const float* bm = (const float*)d_in[18];
  float* out = (float*)d_out;

  // ---- workspace carve (float units); feature buffers channel-major [64][NTOT] ----
  float* ws = (float*)d_ws;
  size_t off = 0;
  auto alloc = [&](size_t nfl) {
    float* ptr = ws + off;
    off += (nfl + 63) & ~(size_t)63;
    return ptr;
  };
  float* bufXW = alloc((size_t)NTOT * 64);
  float* bufH  = alloc((size_t)NTOT * 64);
  float* bufX  = alloc((size_t)NTOT * 64);
  float* dinv_g = alloc(NTOT);
  float* score  = alloc(NTOT);
  float* stanh_g = alloc(NTOT);
  int*   snext_g = (int*)alloc(NTOT);
  uint32_t* packed = (uint32_t*)alloc(EDGES);
  uint16_t* csr    = (uint16_t*)alloc(EDGES / 2);
  uint32_t* rs     = (uint32_t*)alloc(NGR * 1025);
  float* sums3 = alloc(3 * 128);
  float* readout = alloc(NGR * 2 * HID);

  pack_init<<<NGR, 256, 0, stream>>>(ei, packed, csr, rs, dinv_g, sums3, readout);

  const int   kk[3] = {820, 656, 525};
  const float invn[3] = {1.0f / (float)NTOT, 1.0f / (float)(NGR * 820),
                         1.0f / (float)(NGR * 656)};

  for (int L = 0; L < 3; L++) {
    float* sums = sums3 + L * 128;
    if (L == 0)
      gemm_xw<128, false><<<NTOT / 128, 256, 0, stream>>>(x, Wk[0], bufXW, NTOT);
    else
      gemm_xw<64, true><<<NTOT / 128, 256, 0, stream>>>(bufX, Wk[L], bufXW, NTOT);
    edge_agg<<<8 * NGR, 1024, 0, stream>>>(csr, rs, dinv_g, bufXW, bk[L], bufH, sums);
    score_kernel<<<4 * NGR, 256, 0, stream>>>(bufH, sums, gk[L], btk[L], pk[L],
                                              dinv_g, score, stanh_g, invn[L]);
    topk_kernel<<<NGR, 1024, 0, stream>>>(score, packed, dinv_g, snext_g,
                                          kk[L], (L < 2) ? 1 : 0);
    pool_kernel<<<8 * NGR, 256, 0, stream>>>(bufH, sums, gk[L], btk[L],
                                             stanh_g, snext_g,
                                             (L < 2) ? bufX : nullptr, readout,
                                             kk[L], invn[L]);
  }
  final_linear<<<5, 256, 0, stream>>>(readout, Wm, bm, out);
}

// Round 7
// 486.415 us; speedup vs baseline: 3.2452x; 1.0875x over previous
//
#include <hip/hip_runtime.h>
#include <cmath>
#include <cstdint>
#include <cstddef>

#define HID 64
#define NGR 128            // B graphs
#define NTOT 131072        // 128 * 1024 nodes, fixed index space all layers
#define EDGES 1048576      // B * 1024 * 8
#define EPG 8192           // edges per graph

// ---------- once: pack edges, degree hist, CSR (rowstart + u16 src lists), dinv ----------
__global__ __launch_bounds__(256) void pack_init(
    const int* __restrict__ ei, uint32_t* __restrict__ packed,
    uint16_t* __restrict__ csr_g, uint32_t* __restrict__ rs_g,
    float* __restrict__ dinv_g, float* __restrict__ sums3,
    float* __restrict__ readout) {
  __shared__ int hist[1024];
  __shared__ int part[256];
  __shared__ int cursor[1024];
  int b = blockIdx.x, t = threadIdx.x;
  for (int i = t; i < 1024; i += 256) hist[i] = 0;
  __syncthreads();
  int ebase = b * EPG, nbase = b << 10;
  for (int e = t; e < EPG; e += 256) {
    uint32_t s = (uint32_t)(ei[ebase + e] - nbase);
    uint32_t d = (uint32_t)(ei[EDGES + ebase + e] - nbase);
    packed[ebase + e] = s | (d << 10);
    atomicAdd(&hist[(int)d], 1);
  }
  __syncthreads();
  int h0 = hist[t * 4], h1 = hist[t * 4 + 1], h2 = hist[t * 4 + 2], h3 = hist[t * 4 + 3];
  int tot = h0 + h1 + h2 + h3;
  part[t] = tot;
  __syncthreads();
  for (int off = 1; off < 256; off <<= 1) {
    int v = (t >= off) ? part[t - off] : 0;
    __syncthreads();
    part[t] += v;
    __syncthreads();
  }
  int excl = part[t] - tot;
  int r0 = excl, r1 = r0 + h0, r2 = r1 + h1, r3 = r2 + h2;
  cursor[t * 4 + 0] = r0; cursor[t * 4 + 1] = r1;
  cursor[t * 4 + 2] = r2; cursor[t * 4 + 3] = r3;
  uint32_t* rg = rs_g + b * 1025;
  rg[t * 4 + 0] = r0; rg[t * 4 + 1] = r1; rg[t * 4 + 2] = r2; rg[t * 4 + 3] = r3;
  if (t == 255) rg[1024] = EPG;
  for (int i = t; i < 1024; i += 256)
    dinv_g[(b << 10) + i] = rsqrtf((float)hist[i] + 1.0f);
  __syncthreads();
  for (int e = t; e < EPG; e += 256) {
    uint32_t pk = packed[ebase + e];
    int d = (pk >> 10) & 1023;
    int idx = atomicAdd(&cursor[d], 1);
    csr_g[ebase + idx] = (uint16_t)(pk & 1023);
  }
  if (b < 3 && t < 128) sums3[b * 128 + t] = 0.0f;
  if (t < 128) readout[b * 128 + t] = 0.0f;
}

// ---------- xw^T = (X @ W)^T.  X row-major [N,DIN] (TIN=0) or channel-major [DIN,N] (TIN=1).
template<int DIN, bool TIN>
__global__ __launch_bounds__(256) void gemm_xw(
    const float* __restrict__ X, const float* __restrict__ W,
    float* __restrict__ XWT, int n_nodes) {
  __shared__ float sW[32 * HID];       // 8 KB
  __shared__ float sX[32 * 132];       // 16.5 KB  (k-major, node inner, pad 4)
  const int t = threadIdx.x;
  const int cq = t & 15, ng = t >> 4;
  const int c4 = cq * 4;
  const int node0 = blockIdx.x * 128;
  const size_t Nn = (size_t)n_nodes;
  float acc[8][4];
#pragma unroll
  for (int n = 0; n < 8; n++) { acc[n][0]=0.f; acc[n][1]=0.f; acc[n][2]=0.f; acc[n][3]=0.f; }

  for (int k0 = 0; k0 < DIN; k0 += 32) {
    ((float4*)sW)[t * 2 + 0] = ((const float4*)(W + (size_t)k0 * HID))[t * 2 + 0];
    ((float4*)sW)[t * 2 + 1] = ((const float4*)(W + (size_t)k0 * HID))[t * 2 + 1];
    if (TIN) {
#pragma unroll
      for (int it = 0; it < 4; it++) {
        int slot = t + it * 256;
        int row = slot >> 5, col4 = (slot & 31) * 4;
        *(float4*)(sX + row * 132 + col4) =
            *(const float4*)(X + (size_t)(k0 + row) * Nn + node0 + col4);
      }
    } else {
      int i4 = (t & 7) * 4;
      int nl = t >> 3;
#pragma unroll
      for (int rep = 0; rep < 4; rep++) {
        int nn = nl + rep * 32;
        float4 v = *(const float4*)(X + (size_t)(node0 + nn) * DIN + k0 + i4);
        sX[(i4 + 0) * 132 + nn] = v.x;
        sX[(i4 + 1) * 132 + nn] = v.y;
        sX[(i4 + 2) * 132 + nn] = v.z;
        sX[(i4 + 3) * 132 + nn] = v.w;
      }
    }
    __syncthreads();
#pragma unroll 4
    for (int i = 0; i < 32; i++) {
      float4 w = *(const float4*)(sW + i * HID + c4);
      const float* xr = sX + i * 132 + ng * 8;
      float4 xa = *(const float4*)xr;
      float4 xb = *(const float4*)(xr + 4);
      float xn[8] = {xa.x, xa.y, xa.z, xa.w, xb.x, xb.y, xb.z, xb.w};
#pragma unroll
      for (int n = 0; n < 8; n++) {
        acc[n][0] = fmaf(xn[n], w.x, acc[n][0]);
        acc[n][1] = fmaf(xn[n], w.y, acc[n][1]);
        acc[n][2] = fmaf(xn[n], w.z, acc[n][2]);
        acc[n][3] = fmaf(xn[n], w.w, acc[n][3]);
      }
    }
    __syncthreads();
  }
#pragma unroll
  for (int cc = 0; cc < 4; cc++) {
    int row = c4 + cc;
    float* o = XWT + (size_t)row * Nn + node0 + ng * 8;
    *(float4*)(o + 0) = make_float4(acc[0][cc], acc[1][cc], acc[2][cc], acc[3][cc]);
    *(float4*)(o + 4) = make_float4(acc[4][cc], acc[5][cc], acc[6][cc], acc[7][cc]);
  }
}

// ---------- CSR aggregate (no atomics) + self-loop + bias + masked BN sums ----------
__global__ __launch_bounds__(1024, 8) void edge_agg(
    const uint16_t* __restrict__ csr_g, const uint32_t* __restrict__ rs_g,
    const float* __restrict__ dinv_g, const float* __restrict__ xwT,
    const float* __restrict__ bias, float* __restrict__ hT,
    float* __restrict__ sums) {
  __shared__ float xws[8 * 1028];      // prescaled xw*dinv; stride 1028: 8ch -> 8 banks
  __shared__ float dv[1024];
  __shared__ uint32_t rs[1025];
  __shared__ uint16_t csr_s[8192];
  __shared__ float sredS[16][8], sredQ[16][8];
  const int g = blockIdx.x & 127;
  const int q = blockIdx.x >> 7;
  const int c0 = q * 8;
  const int t = threadIdx.x;
  const int gbase = g << 10;

  dv[t] = dinv_g[gbase + t];
  if (t < 1024) rs[t] = rs_g[g * 1025 + t];
  if (t == 0) rs[1024] = EPG;
  ((uint4*)csr_s)[t] = ((const uint4*)(csr_g + (size_t)g * EPG))[t];
  for (int slot = t; slot < 2048; slot += 1024) {
    int c = slot >> 8, pos4 = (slot & 255) * 4;
    float4 v = *(const float4*)(xwT + (size_t)(c0 + c) * NTOT + gbase + pos4);
    float4 dd = *(const float4*)(dinv_g + gbase + pos4);
    v.x *= dd.x; v.y *= dd.y; v.z *= dd.z; v.w *= dd.w;
    *(float4*)(xws + c * 1028 + pos4) = v;
  }
  __syncthreads();

  const int c = t & 7, j = t >> 3;
  const float* xc = xws + c * 1028;
  const float bv = bias[c0 + c];
  float* hrow = hT + (size_t)(c0 + c) * NTOT + gbase;
  float S = 0.0f, Q = 0.0f;
  for (int d = j; d < 1024; d += 128) {
    float dvd = dv[d];
    if (dvd == 0.0f) continue;
    int e = rs[d], e1 = rs[d + 1];
    float a0 = 0.0f, a1 = 0.0f;
    for (; e + 2 <= e1; e += 2) {
      int s0 = csr_s[e], s1 = csr_s[e + 1];
      a0 += xc[s0];
      a1 += xc[s1];
    }
    if (e < e1) a0 += xc[csr_s[e]];
    float hv = (a0 + a1 + xc[d]) * dvd + bv;
    hrow[d] = hv;
    S += hv; Q += hv * hv;
  }
#pragma unroll
  for (int m = 8; m < 64; m <<= 1) { S += __shfl_xor(S, m); Q += __shfl_xor(Q, m); }
  {
    int lane = t & 63, w = t >> 6;
    if (lane < 8) { sredS[w][lane] = S; sredQ[w][lane] = Q; }
  }
  __syncthreads();
  if (t < 8) {
    float a = 0.0f;
    for (int w2 = 0; w2 < 16; w2++) a += sredS[w2][t];
    atomicAdd(&sums[c0 + t], a);
  } else if (t < 16) {
    int cc = t - 8;
    float a = 0.0f;
    for (int w2 = 0; w2 < 16; w2++) a += sredQ[w2][cc];
    atomicAdd(&sums[64 + cc + c0], a);
  }
}

// ---------- scores: BN+ReLU+dot(p) per node; grid = NGR*4 x 256 ----------
__global__ __launch_bounds__(256) void score_kernel(
    const float* __restrict__ hT, const float* __restrict__ sums,
    const float* __restrict__ gamma, const float* __restrict__ beta,
    const float* __restrict__ p, const float* __restrict__ dinv_g,
    float* __restrict__ score, float* __restrict__ stanh_g, float inv_n) {
  __shared__ float ssc[64], ssh[64], sp[64];
  __shared__ float sipn;
  int b = blockIdx.x >> 2, seg = (blockIdx.x & 3) << 8;
  int t = threadIdx.x;
  int node = (b << 10) + seg + t;
  if (t < 64) {
    float mu = sums[t] * inv_n;
    float var = fmaxf(sums[64 + t] * inv_n - mu * mu, 0.0f);
    float sc = rsqrtf(var + 1e-5f) * gamma[t];
    ssc[t] = sc; ssh[t] = beta[t] - mu * sc;
    sp[t] = p[t];
  }
  __syncthreads();
  if (t == 0) {
    float s = 0.0f;
    for (int i = 0; i < 64; i++) s += sp[i] * sp[i];
    sipn = rsqrtf(s);
  }
  __syncthreads();
  const float* hp = hT + node;
  float s0 = 0.0f;
#pragma unroll 16
  for (int c = 0; c < 64; c++) {
    float y = fmaxf(fmaf(hp[(size_t)c * NTOT], ssc[c], ssh[c]), 0.0f);
    s0 = fmaf(y, sp[c], s0);
  }
  float v0 = s0 * sipn;
  score[node] = (dinv_g[node] > 0.0f) ? v0 : -INFINITY;
  stanh_g[node] = tanhf(v0);
}

// ---------- topk: 4 blocks/graph, 4-way j-split rank count -> kept mask ----------
// blockIdx = b*4 + p ; block ranks nodes [p*256, p*256+256)
__global__ __launch_bounds__(1024) void topk_kernel(
    const float* __restrict__ score, int* __restrict__ snext_g, int k) {
  __shared__ float __align__(16) ssc2[4 * 260];   // quarter q at offset q*260
  int b = blockIdx.x >> 2, p = blockIdx.x & 3;
  int t = threadIdx.x;
  int gbase = b << 10;
  float sv = score[gbase + t];
  ssc2[(t >> 8) * 260 + (t & 255)] = sv;
  __syncthreads();
  int il = t >> 2, jq = t & 3;          // node i = p*256+il ; j-quarter jq
  int gi = p * 256 + il;
  float my = ssc2[(gi >> 8) * 260 + (gi & 255)];
  const float4* base = (const float4*)(ssc2 + jq * 260);
  int jbase = jq * 256;
  int r = 0;
#pragma unroll 8
  for (int m = 0; m < 64; m++) {
    float4 v = base[m];
    int j0 = jbase + m * 4;
    r += (v.x > my) || (v.x == my && (j0 + 0) < gi);
    r += (v.y > my) || (v.y == my && (j0 + 1) < gi);
    r += (v.z > my) || (v.z == my && (j0 + 2) < gi);
    r += (v.w > my) || (v.w == my && (j0 + 3) < gi);
  }
  r += __shfl_xor(r, 1);
  r += __shfl_xor(r, 2);
  if (jq == 0) snext_g[gbase + gi] = (r < k) ? 1 : 0;
}

// ---------- masked pool + readout accumulate + next-layer dinv (CSR walk, no atomics) ----------
// grid = 8*NGR x 256 ; block (g,q): channels q*8..q*8+7, and dsts q*128..q*128+127 for deg
__global__ __launch_bounds__(256) void pool_kernel(
    const float* __restrict__ hT, const float* __restrict__ sums,
    const float* __restrict__ gamma, const float* __restrict__ beta,
    const float* __restrict__ stanh_g, const int* __restrict__ snext_g,
    const uint16_t* __restrict__ csr_g, const uint32_t* __restrict__ rs_g,
    float* __restrict__ xT_out, float* __restrict__ dinv_g,
    float* __restrict__ readout, int k, float inv_n, int hasNext) {
  __shared__ float ssc[64], ssh[64];
  __shared__ float sth[1024];
  __shared__ int skn[1024];
  __shared__ float redS[4][8], redM[4][8];
  int g = blockIdx.x & 127, q = blockIdx.x >> 7;
  int t = threadIdx.x;
  int gbase = g << 10;
  if (t < 64) {
    float mu = sums[t] * inv_n;
    float var = fmaxf(sums[64 + t] * inv_n - mu * mu, 0.0f);
    float sc = rsqrtf(var + 1e-5f) * gamma[t];
    ssc[t] = sc; ssh[t] = beta[t] - mu * sc;
  }
  for (int i = t; i < 1024; i += 256) {
    sth[i] = stanh_g[gbase + i];
    skn[i] = snext_g[gbase + i];
  }
  __syncthreads();
  int lane = t & 63, w = t >> 6;
#pragma unroll
  for (int i = 0; i < 8; i++) {
    int c = q * 8 + i;
    const float* hrow = hT + (size_t)c * NTOT + gbase;
    float* xrow = xT_out ? (xT_out + (size_t)c * NTOT + gbase) : nullptr;
    float scc = ssc[c], shh = ssh[c];
    float S = 0.0f, M = -INFINITY;
    for (int nd = t; nd < 1024; nd += 256) {
      bool kn = skn[nd] != 0;
      float y = fmaxf(fmaf(hrow[nd], scc, shh), 0.0f) * sth[nd];
      y = kn ? y : 0.0f;
      if (xrow) xrow[nd] = y;
      S += y;
      if (kn) M = fmaxf(M, y);
    }
#pragma unroll
    for (int m = 1; m < 64; m <<= 1) {
      S += __shfl_xor(S, m);
      M = fmaxf(M, __shfl_xor(M, m));
    }
    if (lane == 0) { redS[w][i] = S; redM[w][i] = M; }
  }
  // next-layer degree via CSR walk against kept mask (no atomics)
  if (hasNext && t < 128) {
    int d = q * 128 + t;
    if (skn[d]) {
      uint32_t e0 = rs_g[g * 1025 + d], e1 = rs_g[g * 1025 + d + 1];
      const uint16_t* row = csr_g + (size_t)g * EPG;
      int cnt = 0;
      for (uint32_t e = e0; e < e1; e++) cnt += skn[row[e]];
      dinv_g[gbase + d] = rsqrtf((float)cnt + 1.0f);
    } else {
      dinv_g[gbase + d] = 0.0f;
    }
  }
  __syncthreads();
  if (t < 8) {
    float S = redS[0][t] + redS[1][t] + redS[2][t] + redS[3][t];
    readout[g * 128 + q * 8 + t] += S / (float)k;
  } else if (t < 16) {
    int i = t - 8;
    float M = fmaxf(fmaxf(redM[0][i], redM[1][i]), fmaxf(redM[2][i], redM[3][i]));
    readout[g * 128 + 64 + q * 8 + i] += M;
  }
}

// ---------------- out = readout @ Wm + bm ----------------
__global__ __launch_bounds__(256) void final_linear(
    const float* __restrict__ readout, const float* __restrict__ Wm,
    const float* __restrict__ bm, float* __restrict__ out) {
  int idx = blockIdx.x * 256 + threadIdx.x;
  if (idx >= NGR * 10) return;
  int b = idx / 10, o = idx - b * 10;
  float acc = bm[o];
  const float* r = readout + (size_t)b * 128;
  for (int c = 0; c < 128; c++) acc = fmaf(r[c], Wm[c * 10 + o], acc);
  out[idx] = acc;
}

extern "C" void kernel_launch(void* const* d_in, const int* in_sizes, int n_in,
                              void* d_out, int out_size, void* d_ws, size_t ws_size,
                              hipStream_t stream) {
  (void)in_sizes; (void)n_in; (void)out_size; (void)ws_size;
  const float* x  = (const float*)d_in[0];
  const int*   ei = (const int*)d_in[1];
  const float* Wk[3]  = {(const float*)d_in[2],  (const float*)d_in[7],  (const float*)d_in[12]};
  const float* bk[3]  = {(const float*)d_in[3],  (const float*)d_in[8],  (const float*)d_in[13]};
  const float* gk[3]  = {(const float*)d_in[4],  (const float*)d_in[9],  (const float*)d_in[14]};
  const float* btk[3] = {(const float*)d_in[5],  (const float*)d_in[10], (const float*)d_in[15]};
  const float* pk[3]  = {(const float*)d_in[6],  (const float*)d_in[11], (const float*)d_in[16]};
  const float* Wm = (const float*)d_in[17];
  const float* bm = (const float*)d_in[18];
  float* out = (float*)d_out;

  // ---- workspace carve (float units); feature buffers channel-major [64][NTOT] ----
  float* ws = (float*)d_ws;
  size_t off = 0;
  auto alloc = [&](size_t nfl) {
    float* ptr = ws + off;
    off += (nfl + 63) & ~(size_t)63;
    return ptr;
  };
  float* bufXW = alloc((size_t)NTOT * 64);
  float* bufH  = alloc((size_t)NTOT * 64);
  float* bufX  = alloc((size_t)NTOT * 64);
  float* dinv_g = alloc(NTOT);
  float* score  = alloc(NTOT);
  float* stanh_g = alloc(NTOT);
  int*   snext_g = (int*)alloc(NTOT);
  uint32_t* packed = (uint32_t*)alloc(EDGES);
  uint16_t* csr    = (uint16_t*)alloc(EDGES / 2);
  uint32_t* rs     = (uint32_t*)alloc(NGR * 1025);
  float* sums3 = alloc(3 * 128);
  float* readout = alloc(NGR * 2 * HID);

  pack_init<<<NGR, 256, 0, stream>>>(ei, packed, csr, rs, dinv_g, sums3, readout);

  const int   kk[3] = {820, 656, 525};
  const float invn[3] = {1.0f / (float)NTOT, 1.0f / (float)(NGR * 820),
                         1.0f / (float)(NGR * 656)};

  for (int L = 0; L < 3; L++) {
    float* sums = sums3 + L * 128;
    if (L == 0)
      gemm_xw<128, false><<<NTOT / 128, 256, 0, stream>>>(x, Wk[0], bufXW, NTOT);
    else
      gemm_xw<64, true><<<NTOT / 128, 256, 0, stream>>>(bufX, Wk[L], bufXW, NTOT);
    edge_agg<<<8 * NGR, 1024, 0, stream>>>(csr, rs, dinv_g, bufXW, bk[L], bufH, sums);
    score_kernel<<<4 * NGR, 256, 0, stream>>>(bufH, sums, gk[L], btk[L], pk[L],
                                              dinv_g, score, stanh_g, invn[L]);
    topk_kernel<<<4 * NGR, 1024, 0, stream>>>(score, snext_g, kk[L]);
    pool_kernel<<<8 * NGR, 256, 0, stream>>>(bufH, sums, gk[L], btk[L],
                                             stanh_g, snext_g, csr, rs,
                                             (L < 2) ? bufX : nullptr, dinv_g,
                                             readout, kk[L], invn[L],
                                             (L < 2) ? 1 : 0);
  }
  final_linear<<<5, 256, 0, stream>>>(readout, Wm, bm, out);
}

// Round 8
// 480.355 us; speedup vs baseline: 3.2861x; 1.0126x over previous
//
#include <hip/hip_runtime.h>
#include <cmath>
#include <cstdint>
#include <cstddef>

#define HID 64
#define NGR 128            // B graphs
#define NTOT 131072        // 128 * 1024 nodes, fixed index space all layers
#define EDGES 1048576      // B * 1024 * 8
#define EPG 8192           // edges per graph

// ---------- once: pack edges, degree hist, CSR (rowstart + u16 src lists), dinv ----------
__global__ __launch_bounds__(256) void pack_init(
    const int* __restrict__ ei, uint32_t* __restrict__ packed,
    uint16_t* __restrict__ csr_g, uint32_t* __restrict__ rs_g,
    float* __restrict__ dinv_g, float* __restrict__ sums3,
    float* __restrict__ readout) {
  __shared__ int hist[1024];
  __shared__ int part[256];
  __shared__ int cursor[1024];
  int b = blockIdx.x, t = threadIdx.x;
  for (int i = t; i < 1024; i += 256) hist[i] = 0;
  __syncthreads();
  int ebase = b * EPG, nbase = b << 10;
  for (int e = t; e < EPG; e += 256) {
    uint32_t s = (uint32_t)(ei[ebase + e] - nbase);
    uint32_t d = (uint32_t)(ei[EDGES + ebase + e] - nbase);
    packed[ebase + e] = s | (d << 10);
    atomicAdd(&hist[(int)d], 1);
  }
  __syncthreads();
  int h0 = hist[t * 4], h1 = hist[t * 4 + 1], h2 = hist[t * 4 + 2], h3 = hist[t * 4 + 3];
  int tot = h0 + h1 + h2 + h3;
  part[t] = tot;
  __syncthreads();
  for (int off = 1; off < 256; off <<= 1) {
    int v = (t >= off) ? part[t - off] : 0;
    __syncthreads();
    part[t] += v;
    __syncthreads();
  }
  int excl = part[t] - tot;
  int r0 = excl, r1 = r0 + h0, r2 = r1 + h1, r3 = r2 + h2;
  cursor[t * 4 + 0] = r0; cursor[t * 4 + 1] = r1;
  cursor[t * 4 + 2] = r2; cursor[t * 4 + 3] = r3;
  uint32_t* rg = rs_g + b * 1025;
  rg[t * 4 + 0] = r0; rg[t * 4 + 1] = r1; rg[t * 4 + 2] = r2; rg[t * 4 + 3] = r3;
  if (t == 255) rg[1024] = EPG;
  for (int i = t; i < 1024; i += 256)
    dinv_g[(b << 10) + i] = rsqrtf((float)hist[i] + 1.0f);
  __syncthreads();
  for (int e = t; e < EPG; e += 256) {
    uint32_t pk = packed[ebase + e];
    int d = (pk >> 10) & 1023;
    int idx = atomicAdd(&cursor[d], 1);
    csr_g[ebase + idx] = (uint16_t)(pk & 1023);
  }
  if (b < 3 && t < 128) sums3[b * 128 + t] = 0.0f;
  if (t < 128) readout[b * 128 + t] = 0.0f;
}

// ---------- xw^T = (X @ W)^T.  64-node x 64-ch tile, 8 blocks/CU, grid = N/64 ----------
// X row-major [N,DIN] (TIN=0) or channel-major [DIN,N] (TIN=1). Output XWT [64][N].
template<int DIN, bool TIN>
__global__ __launch_bounds__(256, 8) void gemm_xw(
    const float* __restrict__ X, const float* __restrict__ W,
    float* __restrict__ XWT, int n_nodes) {
  __shared__ float sW[32 * 64];        // 8 KB   (k-major, ch inner)
  __shared__ float sX[32 * 68];        // 8.5 KB (k-major, node inner, pad 4)
  const int t = threadIdx.x;
  const int cq = t & 15, ng = t >> 4;
  const int c4 = cq * 4;
  const int node0 = blockIdx.x * 64;
  const size_t Nn = (size_t)n_nodes;
  float acc[4][4];
#pragma unroll
  for (int n = 0; n < 4; n++) { acc[n][0]=0.f; acc[n][1]=0.f; acc[n][2]=0.f; acc[n][3]=0.f; }

  for (int k0 = 0; k0 < DIN; k0 += 32) {
    // stage 32 rows of W (512 float4, 2 per thread)
    ((float4*)sW)[t]       = ((const float4*)(W + (size_t)k0 * HID))[t];
    ((float4*)sW)[t + 256] = ((const float4*)(W + (size_t)k0 * HID))[t + 256];
    if (TIN) {
      // X [DIN][N]: 32 rows x 64 cols; 16 float4 per row, 2 rows per thread-pass
      int r = t >> 4, c4i = (t & 15) * 4;
      *(float4*)(sX + r * 68 + c4i) =
          *(const float4*)(X + (size_t)(k0 + r) * Nn + node0 + c4i);
      *(float4*)(sX + (r + 16) * 68 + c4i) =
          *(const float4*)(X + (size_t)(k0 + r + 16) * Nn + node0 + c4i);
    } else {
      // X [N][DIN]: 64 node-rows x 32-k chunk; transpose into LDS
      int i4 = (t & 7) * 4, nn = t >> 3;          // nn 0..31
      float4 v0 = *(const float4*)(X + (size_t)(node0 + nn) * DIN + k0 + i4);
      float4 v1 = *(const float4*)(X + (size_t)(node0 + nn + 32) * DIN + k0 + i4);
      sX[(i4 + 0) * 68 + nn] = v0.x;
      sX[(i4 + 1) * 68 + nn] = v0.y;
      sX[(i4 + 2) * 68 + nn] = v0.z;
      sX[(i4 + 3) * 68 + nn] = v0.w;
      sX[(i4 + 0) * 68 + nn + 32] = v1.x;
      sX[(i4 + 1) * 68 + nn + 32] = v1.y;
      sX[(i4 + 2) * 68 + nn + 32] = v1.z;
      sX[(i4 + 3) * 68 + nn + 32] = v1.w;
    }
    __syncthreads();
#pragma unroll 8
    for (int i = 0; i < 32; i++) {
      float4 w = *(const float4*)(sW + i * HID + c4);
      float4 xv = *(const float4*)(sX + i * 68 + ng * 4);
      float xn[4] = {xv.x, xv.y, xv.z, xv.w};
#pragma unroll
      for (int n = 0; n < 4; n++) {
        acc[n][0] = fmaf(xn[n], w.x, acc[n][0]);
        acc[n][1] = fmaf(xn[n], w.y, acc[n][1]);
        acc[n][2] = fmaf(xn[n], w.z, acc[n][2]);
        acc[n][3] = fmaf(xn[n], w.w, acc[n][3]);
      }
    }
    __syncthreads();
  }
#pragma unroll
  for (int cc = 0; cc < 4; cc++) {
    float* o = XWT + (size_t)(c4 + cc) * Nn + node0 + ng * 4;
    *(float4*)o = make_float4(acc[0][cc], acc[1][cc], acc[2][cc], acc[3][cc]);
  }
}

// ---------- CSR aggregate (no atomics) + self-loop + bias + masked BN sums ----------
__global__ __launch_bounds__(1024, 8) void edge_agg(
    const uint16_t* __restrict__ csr_g, const uint32_t* __restrict__ rs_g,
    const float* __restrict__ dinv_g, const float* __restrict__ xwT,
    const float* __restrict__ bias, float* __restrict__ hT,
    float* __restrict__ sums) {
  __shared__ float xws[8 * 1028];      // prescaled xw*dinv; stride 1028: 8ch -> 8 banks
  __shared__ float dv[1024];
  __shared__ uint32_t rs[1025];
  __shared__ uint16_t csr_s[8192];
  __shared__ float sredS[16][8], sredQ[16][8];
  const int g = blockIdx.x & 127;
  const int q = blockIdx.x >> 7;
  const int c0 = q * 8;
  const int t = threadIdx.x;
  const int gbase = g << 10;

  dv[t] = dinv_g[gbase + t];
  if (t < 1024) rs[t] = rs_g[g * 1025 + t];
  if (t == 0) rs[1024] = EPG;
  ((uint4*)csr_s)[t] = ((const uint4*)(csr_g + (size_t)g * EPG))[t];
  for (int slot = t; slot < 2048; slot += 1024) {
    int c = slot >> 8, pos4 = (slot & 255) * 4;
    float4 v = *(const float4*)(xwT + (size_t)(c0 + c) * NTOT + gbase + pos4);
    float4 dd = *(const float4*)(dinv_g + gbase + pos4);
    v.x *= dd.x; v.y *= dd.y; v.z *= dd.z; v.w *= dd.w;
    *(float4*)(xws + c * 1028 + pos4) = v;
  }
  __syncthreads();

  const int c = t & 7, j = t >> 3;
  const float* xc = xws + c * 1028;
  const float bv = bias[c0 + c];
  float* hrow = hT + (size_t)(c0 + c) * NTOT + gbase;
  float S = 0.0f, Q = 0.0f;
  for (int d = j; d < 1024; d += 128) {
    float dvd = dv[d];
    if (dvd == 0.0f) continue;
    int e = rs[d], e1 = rs[d + 1];
    float a0 = 0.0f, a1 = 0.0f;
    for (; e + 2 <= e1; e += 2) {
      int s0 = csr_s[e], s1 = csr_s[e + 1];
      a0 += xc[s0];
      a1 += xc[s1];
    }
    if (e < e1) a0 += xc[csr_s[e]];
    float hv = (a0 + a1 + xc[d]) * dvd + bv;
    hrow[d] = hv;
    S += hv; Q += hv * hv;
  }
#pragma unroll
  for (int m = 8; m < 64; m <<= 1) { S += __shfl_xor(S, m); Q += __shfl_xor(Q, m); }
  {
    int lane = t & 63, w = t >> 6;
    if (lane < 8) { sredS[w][lane] = S; sredQ[w][lane] = Q; }
  }
  __syncthreads();
  if (t < 8) {
    float a = 0.0f;
    for (int w2 = 0; w2 < 16; w2++) a += sredS[w2][t];
    atomicAdd(&sums[c0 + t], a);
  } else if (t < 16) {
    int cc = t - 8;
    float a = 0.0f;
    for (int w2 = 0; w2 < 16; w2++) a += sredQ[w2][cc];
    atomicAdd(&sums[64 + cc + c0], a);
  }
}

// ---------- scores: BN+ReLU+dot(p) per node; grid = NGR*4 x 256 ----------
__global__ __launch_bounds__(256) void score_kernel(
    const float* __restrict__ hT, const float* __restrict__ sums,
    const float* __restrict__ gamma, const float* __restrict__ beta,
    const float* __restrict__ p, const float* __restrict__ dinv_g,
    float* __restrict__ score, float* __restrict__ stanh_g, float inv_n) {
  __shared__ float ssc[64], ssh[64], sp[64];
  __shared__ float sipn;
  int b = blockIdx.x >> 2, seg = (blockIdx.x & 3) << 8;
  int t = threadIdx.x;
  int node = (b << 10) + seg + t;
  if (t < 64) {
    float mu = sums[t] * inv_n;
    float var = fmaxf(sums[64 + t] * inv_n - mu * mu, 0.0f);
    float sc = rsqrtf(var + 1e-5f) * gamma[t];
    ssc[t] = sc; ssh[t] = beta[t] - mu * sc;
    sp[t] = p[t];
  }
  __syncthreads();
  if (t == 0) {
    float s = 0.0f;
    for (int i = 0; i < 64; i++) s += sp[i] * sp[i];
    sipn = rsqrtf(s);
  }
  __syncthreads();
  const float* hp = hT + node;
  float s0 = 0.0f;
#pragma unroll 16
  for (int c = 0; c < 64; c++) {
    float y = fmaxf(fmaf(hp[(size_t)c * NTOT], ssc[c], ssh[c]), 0.0f);
    s0 = fmaf(y, sp[c], s0);
  }
  float v0 = s0 * sipn;
  score[node] = (dinv_g[node] > 0.0f) ? v0 : -INFINITY;
  stanh_g[node] = tanhf(v0);
}

// ---------- topk: 4 blocks/graph, 4-way j-split rank count -> kept mask ----------
__global__ __launch_bounds__(1024) void topk_kernel(
    const float* __restrict__ score, int* __restrict__ snext_g, int k) {
  __shared__ float __align__(16) ssc2[4 * 260];   // quarter q at offset q*260
  int b = blockIdx.x >> 2, p = blockIdx.x & 3;
  int t = threadIdx.x;
  int gbase = b << 10;
  float sv = score[gbase + t];
  ssc2[(t >> 8) * 260 + (t & 255)] = sv;
  __syncthreads();
  int il = t >> 2, jq = t & 3;
  int gi = p * 256 + il;
  float my = ssc2[(gi >> 8) * 260 + (gi & 255)];
  const float4* base = (const float4*)(ssc2 + jq * 260);
  int jbase = jq * 256;
  int r = 0;
#pragma unroll 8
  for (int m = 0; m < 64; m++) {
    float4 v = base[m];
    int j0 = jbase + m * 4;
    r += (v.x > my) || (v.x == my && (j0 + 0) < gi);
    r += (v.y > my) || (v.y == my && (j0 + 1) < gi);
    r += (v.z > my) || (v.z == my && (j0 + 2) < gi);
    r += (v.w > my) || (v.w == my && (j0 + 3) < gi);
  }
  r += __shfl_xor(r, 1);
  r += __shfl_xor(r, 2);
  if (jq == 0) snext_g[gbase + gi] = (r < k) ? 1 : 0;
}

// ---------- masked pool + readout accumulate + next-layer dinv (CSR walk, no atomics) ----------
__global__ __launch_bounds__(256) void pool_kernel(
    const float* __restrict__ hT, const float* __restrict__ sums,
    const float* __restrict__ gamma, const float* __restrict__ beta,
    const float* __restrict__ stanh_g, const int* __restrict__ snext_g,
    const uint16_t* __restrict__ csr_g, const uint32_t* __restrict__ rs_g,
    float* __restrict__ xT_out, float* __restrict__ dinv_g,
    float* __restrict__ readout, int k, float inv_n, int hasNext) {
  __shared__ float ssc[64], ssh[64];
  __shared__ float sth[1024];
  __shared__ int skn[1024];
  __shared__ float redS[4][8], redM[4][8];
  int g = blockIdx.x & 127, q = blockIdx.x >> 7;
  int t = threadIdx.x;
  int gbase = g << 10;
  if (t < 64) {
    float mu = sums[t] * inv_n;
    float var = fmaxf(sums[64 + t] * inv_n - mu * mu, 0.0f);
    float sc = rsqrtf(var + 1e-5f) * gamma[t];
    ssc[t] = sc; ssh[t] = beta[t] - mu * sc;
  }
  for (int i = t; i < 1024; i += 256) {
    sth[i] = stanh_g[gbase + i];
    skn[i] = snext_g[gbase + i];
  }
  __syncthreads();
  int lane = t & 63, w = t >> 6;
#pragma unroll
  for (int i = 0; i < 8; i++) {
    int c = q * 8 + i;
    const float* hrow = hT + (size_t)c * NTOT + gbase;
    float* xrow = xT_out ? (xT_out + (size_t)c * NTOT + gbase) : nullptr;
    float scc = ssc[c], shh = ssh[c];
    float S = 0.0f, M = -INFINITY;
    for (int nd = t; nd < 1024; nd += 256) {
      bool kn = skn[nd] != 0;
      float y = fmaxf(fmaf(hrow[nd], scc, shh), 0.0f) * sth[nd];
      y = kn ? y : 0.0f;
      if (xrow) xrow[nd] = y;
      S += y;
      if (kn) M = fmaxf(M, y);
    }
#pragma unroll
    for (int m = 1; m < 64; m <<= 1) {
      S += __shfl_xor(S, m);
      M = fmaxf(M, __shfl_xor(M, m));
    }
    if (lane == 0) { redS[w][i] = S; redM[w][i] = M; }
  }
  if (hasNext && t < 128) {
    int d = q * 128 + t;
    if (skn[d]) {
      uint32_t e0 = rs_g[g * 1025 + d], e1 = rs_g[g * 1025 + d + 1];
      const uint16_t* row = csr_g + (size_t)g * EPG;
      int cnt = 0;
      for (uint32_t e = e0; e < e1; e++) cnt += skn[row[e]];
      dinv_g[gbase + d] = rsqrtf((float)cnt + 1.0f);
    } else {
      dinv_g[gbase + d] = 0.0f;
    }
  }
  __syncthreads();
  if (t < 8) {
    float S = redS[0][t] + redS[1][t] + redS[2][t] + redS[3][t];
    readout[g * 128 + q * 8 + t] += S / (float)k;
  } else if (t < 16) {
    int i = t - 8;
    float M = fmaxf(fmaxf(redM[0][i], redM[1][i]), fmaxf(redM[2][i], redM[3][i]));
    readout[g * 128 + 64 + q * 8 + i] += M;
  }
}

// ---------------- out = readout @ Wm + bm ----------------
__global__ __launch_bounds__(256) void final_linear(
    const float* __restrict__ readout, const float* __restrict__ Wm,
    const float* __restrict__ bm, float* __restrict__ out) {
  int idx = blockIdx.x * 256 + threadIdx.x;
  if (idx >= NGR * 10) return;
  int b = idx / 10, o = idx - b * 10;
  float acc = bm[o];
  const float* r = readout + (size_t)b * 128;
  for (int c = 0; c < 128; c++) acc = fmaf(r[c], Wm[c * 10 + o], acc);
  out[idx] = acc;
}

extern "C" void kernel_launch(void* const* d_in, const int* in_sizes, int n_in,
                              void* d_out, int out_size, void* d_ws, size_t ws_size,
                              hipStream_t stream) {
  (void)in_sizes; (void)n_in; (void)out_size; (void)ws_size;
  const float* x  = (const float*)d_in[0];
  const int*   ei = (const int*)d_in[1];
  const float* Wk[3]  = {(const float*)d_in[2],  (const float*)d_in[7],  (const float*)d_in[12]};
  const float* bk[3]  = {(const float*)d_in[3],  (const float*)d_in[8],  (const float*)d_in[13]};
  const float* gk[3]  = {(const float*)d_in[4],  (const float*)d_in[9],  (const float*)d_in[14]};
  const float* btk[3] = {(const float*)d_in[5],  (const float*)d_in[10], (const float*)d_in[15]};
  const float* pk[3]  = {(const float*)d_in[6],  (const float*)d_in[11], (const float*)d_in[16]};
  const float* Wm = (const float*)d_in[17];
  const float* bm = (const float*)d_in[18];
  float* out = (float*)d_out;

  // ---- workspace carve (float units); feature buffers channel-major [64][NTOT] ----
  float* ws = (float*)d_ws;
  size_t off = 0;
  auto alloc = [&](size_t nfl) {
    float* ptr = ws + off;
    off += (nfl + 63) & ~(size_t)63;
    return ptr;
  };
  float* bufXW = alloc((size_t)NTOT * 64);
  float* bufH  = alloc((size_t)NTOT * 64);
  float* bufX  = alloc((size_t)NTOT * 64);
  float* dinv_g = alloc(NTOT);
  float* score  = alloc(NTOT);
  float* stanh_g = alloc(NTOT);
  int*   snext_g = (int*)alloc(NTOT);
  uint32_t* packed = (uint32_t*)alloc(EDGES);
  uint16_t* csr    = (uint16_t*)alloc(EDGES / 2);
  uint32_t* rs     = (uint32_t*)alloc(NGR * 1025);
  float* sums3 = alloc(3 * 128);
  float* readout = alloc(NGR * 2 * HID);

  pack_init<<<NGR, 256, 0, stream>>>(ei, packed, csr, rs, dinv_g, sums3, readout);

  const int   kk[3] = {820, 656, 525};
  const float invn[3] = {1.0f / (float)NTOT, 1.0f / (float)(NGR * 820),
                         1.0f / (float)(NGR * 656)};

  for (int L = 0; L < 3; L++) {
    float* sums = sums3 + L * 128;
    if (L == 0)
      gemm_xw<128, false><<<NTOT / 64, 256, 0, stream>>>(x, Wk[0], bufXW, NTOT);
    else
      gemm_xw<64, true><<<NTOT / 64, 256, 0, stream>>>(bufX, Wk[L], bufXW, NTOT);
    edge_agg<<<8 * NGR, 1024, 0, stream>>>(csr, rs, dinv_g, bufXW, bk[L], bufH, sums);
    score_kernel<<<4 * NGR, 256, 0, stream>>>(bufH, sums, gk[L], btk[L], pk[L],
                                              dinv_g, score, stanh_g, invn[L]);
    topk_kernel<<<4 * NGR, 1024, 0, stream>>>(score, snext_g, kk[L]);
    pool_kernel<<<8 * NGR, 256, 0, stream>>>(bufH, sums, gk[L], btk[L],
                                             stanh_g, snext_g, csr, rs,
                                             (L < 2) ? bufX : nullptr, dinv_g,
                                             readout, kk[L], invn[L],
                                             (L < 2) ? 1 : 0);
  }
  final_linear<<<5, 256, 0, stream>>>(readout, Wm, bm, out);
}

// Round 9
// 472.411 us; speedup vs baseline: 3.3414x; 1.0168x over previous
//
#include <hip/hip_runtime.h>
#include <cmath>
#include <cstdint>
#include <cstddef>

#define HID 64
#define NGR 128            // B graphs
#define NTOT 131072        // 128 * 1024 nodes, fixed index space all layers
#define EDGES 1048576      // B * 1024 * 8
#define EPG 8192           // edges per graph
#define CPAD 9216          // padded CSR stride (u16): 8192 + 1024 worst-case pads
#define SENT 1024          // sentinel src index -> reads 0

// ---------- once: pack edges, degree hist, even-padded CSR, dinv ----------
__global__ __launch_bounds__(256) void pack_init(
    const int* __restrict__ ei, uint32_t* __restrict__ packed,
    uint16_t* __restrict__ csr_g, uint32_t* __restrict__ rs_g,
    float* __restrict__ dinv_g, float* __restrict__ sums3,
    float* __restrict__ readout) {
  __shared__ int hist[1024];
  __shared__ int part[256];
  __shared__ int cursor[1024];
  int b = blockIdx.x, t = threadIdx.x;
  for (int i = t; i < 1024; i += 256) hist[i] = 0;
  __syncthreads();
  int ebase = b * EPG, nbase = b << 10;
  for (int e = t; e < EPG; e += 256) {
    uint32_t s = (uint32_t)(ei[ebase + e] - nbase);
    uint32_t d = (uint32_t)(ei[EDGES + ebase + e] - nbase);
    packed[ebase + e] = s | (d << 10);
    atomicAdd(&hist[(int)d], 1);
  }
  __syncthreads();
  int h0 = hist[t * 4], h1 = hist[t * 4 + 1], h2 = hist[t * 4 + 2], h3 = hist[t * 4 + 3];
  // even-padded row lengths
  int p0 = h0 + (h0 & 1), p1 = h1 + (h1 & 1), p2 = h2 + (h2 & 1), p3 = h3 + (h3 & 1);
  int tot = p0 + p1 + p2 + p3;
  part[t] = tot;
  __syncthreads();
  for (int off = 1; off < 256; off <<= 1) {
    int v = (t >= off) ? part[t - off] : 0;
    __syncthreads();
    part[t] += v;
    __syncthreads();
  }
  int excl = part[t] - tot;
  int r0 = excl, r1 = r0 + p0, r2 = r1 + p1, r3 = r2 + p2;
  cursor[t * 4 + 0] = r0; cursor[t * 4 + 1] = r1;
  cursor[t * 4 + 2] = r2; cursor[t * 4 + 3] = r3;
  uint32_t* rg = rs_g + b * 1025;
  rg[t * 4 + 0] = r0; rg[t * 4 + 1] = r1; rg[t * 4 + 2] = r2; rg[t * 4 + 3] = r3;
  if (t == 255) rg[1024] = part[255];           // total padded length
  for (int i = t; i < 1024; i += 256)
    dinv_g[(b << 10) + i] = rsqrtf((float)hist[i] + 1.0f);
  __syncthreads();
  uint16_t* cg = csr_g + (size_t)b * CPAD;
  for (int e = t; e < EPG; e += 256) {
    uint32_t pk = packed[ebase + e];
    int d = (pk >> 10) & 1023;
    int idx = atomicAdd(&cursor[d], 1);
    cg[idx] = (uint16_t)(pk & 1023);
  }
  __syncthreads();
  // sentinel fill for odd rows (cursor[d] == pstart[d] + hist[d] now)
  for (int d = t; d < 1024; d += 256)
    if (hist[d] & 1) cg[cursor[d]] = (uint16_t)SENT;
  if (b < 3 && t < 128) sums3[b * 128 + t] = 0.0f;
  if (t < 128) readout[b * 128 + t] = 0.0f;
}

// ---------- xw^T = (X @ W)^T.  256-node x 64-ch tile, thread = 8 nodes x 8 ch ----------
// X row-major [N,DIN] (TIN=0) or channel-major [DIN,N] (TIN=1). Output XWT [64][N].
template<int DIN, bool TIN>
__global__ __launch_bounds__(256, 2) void gemm_xw(
    const float* __restrict__ X, const float* __restrict__ W,
    float* __restrict__ XWT, int n_nodes) {
  __shared__ float sW[32 * 64];        // 8 KB   (k-major, ch inner)
  __shared__ float sX[32 * 260];       // 33.3 KB (k-major, node inner, pad 4)
  const int t = threadIdx.x;
  const int c8 = (t & 7) * 8;
  const int n8 = (t >> 3) * 8;
  const int node0 = blockIdx.x * 256;
  const size_t Nn = (size_t)n_nodes;
  float acc[8][8];
#pragma unroll
  for (int n = 0; n < 8; n++)
#pragma unroll
    for (int c = 0; c < 8; c++) acc[n][c] = 0.0f;

  for (int k0 = 0; k0 < DIN; k0 += 32) {
    // stage 32 rows of W (512 float4, 2 per thread)
    ((float4*)sW)[t]       = ((const float4*)(W + (size_t)k0 * HID))[t];
    ((float4*)sW)[t + 256] = ((const float4*)(W + (size_t)k0 * HID))[t + 256];
    if (TIN) {
      // X [DIN][N]: 32 rows x 256 cols = 2048 f4, 8 per thread
#pragma unroll
      for (int it = 0; it < 8; it++) {
        int slot = t + it * 256;
        int row = slot >> 6, col4 = (slot & 63) * 4;
        *(float4*)(sX + row * 260 + col4) =
            *(const float4*)(X + (size_t)(k0 + row) * Nn + node0 + col4);
      }
    } else {
      // X [N][DIN]: 256 node-rows x 32-k chunk; transpose into LDS
      int i4 = (t & 7) * 4, nn = t >> 3;          // nn 0..31
#pragma unroll
      for (int rep = 0; rep < 8; rep++) {
        int node = nn + rep * 32;
        float4 v = *(const float4*)(X + (size_t)(node0 + node) * DIN + k0 + i4);
        sX[(i4 + 0) * 260 + node] = v.x;
        sX[(i4 + 1) * 260 + node] = v.y;
        sX[(i4 + 2) * 260 + node] = v.z;
        sX[(i4 + 3) * 260 + node] = v.w;
      }
    }
    __syncthreads();
#pragma unroll 4
    for (int i = 0; i < 32; i++) {
      float4 w0 = *(const float4*)(sW + i * 64 + c8);
      float4 w1 = *(const float4*)(sW + i * 64 + c8 + 4);
      float4 x0 = *(const float4*)(sX + i * 260 + n8);
      float4 x1 = *(const float4*)(sX + i * 260 + n8 + 4);
      float xn[8] = {x0.x, x0.y, x0.z, x0.w, x1.x, x1.y, x1.z, x1.w};
      float wn[8] = {w0.x, w0.y, w0.z, w0.w, w1.x, w1.y, w1.z, w1.w};
#pragma unroll
      for (int n = 0; n < 8; n++)
#pragma unroll
        for (int c = 0; c < 8; c++)
          acc[n][c] = fmaf(xn[n], wn[c], acc[n][c]);
    }
    __syncthreads();
  }
#pragma unroll
  for (int cc = 0; cc < 8; cc++) {
    float* o = XWT + (size_t)(c8 + cc) * Nn + node0 + n8;
    *(float4*)(o + 0) = make_float4(acc[0][cc], acc[1][cc], acc[2][cc], acc[3][cc]);
    *(float4*)(o + 4) = make_float4(acc[4][cc], acc[5][cc], acc[6][cc], acc[7][cc]);
  }
}

// ---------- CSR aggregate (paired u32 src reads) + self-loop + bias + BN sums ----------
__global__ __launch_bounds__(1024, 8) void edge_agg(
    const uint16_t* __restrict__ csr_g, const uint32_t* __restrict__ rs_g,
    const float* __restrict__ dinv_g, const float* __restrict__ xwT,
    const float* __restrict__ bias, float* __restrict__ hT,
    float* __restrict__ sums) {
  __shared__ float xws[8 * 1028];      // prescaled xw*dinv; index 1024 = sentinel 0
  __shared__ float dv[1024];
  __shared__ uint32_t rs[1025];
  __shared__ uint32_t csr_s[CPAD / 2]; // 4608 u32 = 18.4 KB (pairs of u16 srcs)
  __shared__ float sredS[16][8], sredQ[16][8];
  const int g = blockIdx.x & 127;
  const int q = blockIdx.x >> 7;
  const int c0 = q * 8;
  const int t = threadIdx.x;
  const int gbase = g << 10;

  dv[t] = dinv_g[gbase + t];
  rs[t] = rs_g[g * 1025 + t];
  if (t == 0) rs[1024] = rs_g[g * 1025 + 1024];
  {
    const uint4* src4 = (const uint4*)(csr_g + (size_t)g * CPAD);
    ((uint4*)csr_s)[t] = src4[t];
    if (t < CPAD / 8 - 1024) ((uint4*)csr_s)[1024 + t] = src4[1024 + t];
  }
  for (int slot = t; slot < 2048; slot += 1024) {
    int c = slot >> 8, pos4 = (slot & 255) * 4;
    float4 v = *(const float4*)(xwT + (size_t)(c0 + c) * NTOT + gbase + pos4);
    float4 dd = *(const float4*)(dinv_g + gbase + pos4);
    v.x *= dd.x; v.y *= dd.y; v.z *= dd.z; v.w *= dd.w;
    *(float4*)(xws + c * 1028 + pos4) = v;
  }
  if (t < 32) xws[(t >> 2) * 1028 + 1024 + (t & 3)] = 0.0f;   // sentinel slots
  __syncthreads();

  const int c = t & 7, j = t >> 3;
  const float* xc = xws + c * 1028;
  const float bv = bias[c0 + c];
  float* hrow = hT + (size_t)(c0 + c) * NTOT + gbase;
  float S = 0.0f, Q = 0.0f;
  for (int d = j; d < 1024; d += 128) {
    float dvd = dv[d];
    if (dvd == 0.0f) continue;
    int e  = rs[d] >> 1;
    int e1 = rs[d + 1] >> 1;
    float a0 = 0.0f, a1 = 0.0f;
    for (; e < e1; e++) {
      uint32_t pk = csr_s[e];
      a0 += xc[pk & 0xFFFFu];
      a1 += xc[pk >> 16];
    }
    float hv = (a0 + a1 + xc[d]) * dvd + bv;
    hrow[d] = hv;
    S += hv; Q += hv * hv;
  }
#pragma unroll
  for (int m = 8; m < 64; m <<= 1) { S += __shfl_xor(S, m); Q += __shfl_xor(Q, m); }
  {
    int lane = t & 63, w = t >> 6;
    if (lane < 8) { sredS[w][lane] = S; sredQ[w][lane] = Q; }
  }
  __syncthreads();
  if (t < 8) {
    float a = 0.0f;
    for (int w2 = 0; w2 < 16; w2++) a += sredS[w2][t];
    atomicAdd(&sums[c0 + t], a);
  } else if (t < 16) {
    int cc = t - 8;
    float a = 0.0f;
    for (int w2 = 0; w2 < 16; w2++) a += sredQ[w2][cc];
    atomicAdd(&sums[64 + cc + c0], a);
  }
}

// ---------- scores: BN+ReLU+dot(p) per node; grid = NGR*4 x 256 ----------
__global__ __launch_bounds__(256) void score_kernel(
    const float* __restrict__ hT, const float* __restrict__ sums,
    const float* __restrict__ gamma, const float* __restrict__ beta,
    const float* __restrict__ p, const float* __restrict__ dinv_g,
    float* __restrict__ score, float* __restrict__ stanh_g, float inv_n) {
  __shared__ float ssc[64], ssh[64], sp[64];
  __shared__ float sipn;
  int b = blockIdx.x >> 2, seg = (blockIdx.x & 3) << 8;
  int t = threadIdx.x;
  int node = (b << 10) + seg + t;
  if (t < 64) {
    float mu = sums[t] * inv_n;
    float var = fmaxf(sums[64 + t] * inv_n - mu * mu, 0.0f);
    float sc = rsqrtf(var + 1e-5f) * gamma[t];
    ssc[t] = sc; ssh[t] = beta[t] - mu * sc;
    sp[t] = p[t];
  }
  __syncthreads();
  if (t == 0) {
    float s = 0.0f;
    for (int i = 0; i < 64; i++) s += sp[i] * sp[i];
    sipn = rsqrtf(s);
  }
  __syncthreads();
  const float* hp = hT + node;
  float s0 = 0.0f;
#pragma unroll 16
  for (int c = 0; c < 64; c++) {
    float y = fmaxf(fmaf(hp[(size_t)c * NTOT], ssc[c], ssh[c]), 0.0f);
    s0 = fmaf(y, sp[c], s0);
  }
  float v0 = s0 * sipn;
  score[node] = (dinv_g[node] > 0.0f) ? v0 : -INFINITY;
  stanh_g[node] = tanhf(v0);
}

// ---------- topk: 4 blocks/graph, 4-way j-split rank count -> kept mask ----------
__global__ __launch_bounds__(1024) void topk_kernel(
    const float* __restrict__ score, int* __restrict__ snext_g, int k) {
  __shared__ float __align__(16) ssc2[4 * 260];   // quarter q at offset q*260
  int b = blockIdx.x >> 2, p = blockIdx.x & 3;
  int t = threadIdx.x;
  int gbase = b << 10;
  float sv = score[gbase + t];
  ssc2[(t >> 8) * 260 + (t & 255)] = sv;
  __syncthreads();
  int il = t >> 2, jq = t & 3;
  int gi = p * 256 + il;
  float my = ssc2[(gi >> 8) * 260 + (gi & 255)];
  const float4* base = (const float4*)(ssc2 + jq * 260);
  int jbase = jq * 256;
  int r = 0;
#pragma unroll 8
  for (int m = 0; m < 64; m++) {
    float4 v = base[m];
    int j0 = jbase + m * 4;
    r += (v.x > my) || (v.x == my && (j0 + 0) < gi);
    r += (v.y > my) || (v.y == my && (j0 + 1) < gi);
    r += (v.z > my) || (v.z == my && (j0 + 2) < gi);
    r += (v.w > my) || (v.w == my && (j0 + 3) < gi);
  }
  r += __shfl_xor(r, 1);
  r += __shfl_xor(r, 2);
  if (jq == 0) snext_g[gbase + gi] = (r < k) ? 1 : 0;
}

// ---------- masked pool + readout accumulate + next-layer dinv (CSR walk) ----------
__global__ __launch_bounds__(256) void pool_kernel(
    const float* __restrict__ hT, const float* __restrict__ sums,
    const float* __restrict__ gamma, const float* __restrict__ beta,
    const float* __restrict__ stanh_g, const int* __restrict__ snext_g,
    const uint16_t* __restrict__ csr_g, const uint32_t* __restrict__ rs_g,
    float* __restrict__ xT_out, float* __restrict__ dinv_g,
    float* __restrict__ readout, int k, float inv_n, int hasNext) {
  __shared__ float ssc[64], ssh[64];
  __shared__ float sth[1024];
  __shared__ int skn[1025];            // [1024] = 0 for sentinel
  __shared__ float redS[4][8], redM[4][8];
  int g = blockIdx.x & 127, q = blockIdx.x >> 7;
  int t = threadIdx.x;
  int gbase = g << 10;
  if (t < 64) {
    float mu = sums[t] * inv_n;
    float var = fmaxf(sums[64 + t] * inv_n - mu * mu, 0.0f);
    float sc = rsqrtf(var + 1e-5f) * gamma[t];
    ssc[t] = sc; ssh[t] = beta[t] - mu * sc;
  }
  for (int i = t; i < 1024; i += 256) {
    sth[i] = stanh_g[gbase + i];
    skn[i] = snext_g[gbase + i];
  }
  if (t == 0) skn[1024] = 0;
  __syncthreads();
  int lane = t & 63, w = t >> 6;
#pragma unroll
  for (int i = 0; i < 8; i++) {
    int c = q * 8 + i;
    const float* hrow = hT + (size_t)c * NTOT + gbase;
    float* xrow = xT_out ? (xT_out + (size_t)c * NTOT + gbase) : nullptr;
    float scc = ssc[c], shh = ssh[c];
    float S = 0.0f, M = -INFINITY;
    for (int nd = t; nd < 1024; nd += 256) {
      bool kn = skn[nd] != 0;
      float y = fmaxf(fmaf(hrow[nd], scc, shh), 0.0f) * sth[nd];
      y = kn ? y : 0.0f;
      if (xrow) xrow[nd] = y;
      S += y;
      if (kn) M = fmaxf(M, y);
    }
#pragma unroll
    for (int m = 1; m < 64; m <<= 1) {
      S += __shfl_xor(S, m);
      M = fmaxf(M, __shfl_xor(M, m));
    }
    if (lane == 0) { redS[w][i] = S; redM[w][i] = M; }
  }
  if (hasNext && t < 128) {
    int d = q * 128 + t;
    if (skn[d]) {
      uint32_t e0 = rs_g[g * 1025 + d], e1 = rs_g[g * 1025 + d + 1];
      const uint16_t* row = csr_g + (size_t)g * CPAD;
      int cnt = 0;
      for (uint32_t e = e0; e < e1; e++) cnt += skn[row[e]];   // sentinel -> 0
      dinv_g[gbase + d] = rsqrtf((float)cnt + 1.0f);
    } else {
      dinv_g[gbase + d] = 0.0f;
    }
  }
  __syncthreads();
  if (t < 8) {
    float S = redS[0][t] + redS[1][t] + redS[2][t] + redS[3][t];
    readout[g * 128 + q * 8 + t] += S / (float)k;
  } else if (t < 16) {
    int i = t - 8;
    float M = fmaxf(fmaxf(redM[0][i], redM[1][i]), fmaxf(redM[2][i], redM[3][i]));
    readout[g * 128 + 64 + q * 8 + i] += M;
  }
}

// ---------------- out = readout @ Wm + bm ----------------
__global__ __launch_bounds__(256) void final_linear(
    const float* __restrict__ readout, const float* __restrict__ Wm,
    const float* __restrict__ bm, float* __restrict__ out) {
  int idx = blockIdx.x * 256 + threadIdx.x;
  if (idx >= NGR * 10) return;
  int b = idx / 10, o = idx - b * 10;
  float acc = bm[o];
  const float* r = readout + (size_t)b * 128;
  for (int c = 0; c < 128; c++) acc = fmaf(r[c], Wm[c * 10 + o], acc);
  out[idx] = acc;
}

extern "C" void kernel_launch(void* const* d_in, const int* in_sizes, int n_in,
                              void* d_out, int out_size, void* d_ws, size_t ws_size,
                              hipStream_t stream) {
  (void)in_sizes; (void)n_in; (void)out_size; (void)ws_size;
  const float* x  = (const float*)d_in[0];
  const int*   ei = (const int*)d_in[1];
  const float* Wk[3]  = {(const float*)d_in[2],  (const float*)d_in[7],  (const float*)d_in[12]};
  const float* bk[3]  = {(const float*)d_in[3],  (const float*)d_in[8],  (const float*)d_in[13]};
  const float* gk[3]  = {(const float*)d_in[4],  (const float*)d_in[9],  (const float*)d_in[14]};
  const float* btk[3] = {(const float*)d_in[5],  (const float*)d_in[10], (const float*)d_in[15]};
  const float* pk[3]  = {(const float*)d_in[6],  (const float*)d_in[11], (const float*)d_in[16]};
  const float* Wm = (const float*)d_in[17];
  const float* bm = (const float*)d_in[18];
  float* out = (float*)d_out;

  // ---- workspace carve (float units); feature buffers channel-major [64][NTOT] ----
  float* ws = (float*)d_ws;
  size_t off = 0;
  auto alloc = [&](size_t nfl) {
    float* ptr = ws + off;
    off += (nfl + 63) & ~(size_t)63;
    return ptr;
  };
  float* bufXW = alloc((size_t)NTOT * 64);
  float* bufH  = alloc((size_t)NTOT * 64);
  float* bufX  = alloc((size_t)NTOT * 64);
  float* dinv_g = alloc(NTOT);
  float* score  = alloc(NTOT);
  float* stanh_g = alloc(NTOT);
  int*   snext_g = (int*)alloc(NTOT);
  uint32_t* packed = (uint32_t*)alloc(EDGES);
  uint16_t* csr    = (uint16_t*)alloc((size_t)NGR * CPAD / 2);
  uint32_t* rs     = (uint32_t*)alloc(NGR * 1025);
  float* sums3 = alloc(3 * 128);
  float* readout = alloc(NGR * 2 * HID);

  pack_init<<<NGR, 256, 0, stream>>>(ei, packed, csr, rs, dinv_g, sums3, readout);

  const int   kk[3] = {820, 656, 525};
  const float invn[3] = {1.0f / (float)NTOT, 1.0f / (float)(NGR * 820),
                         1.0f / (float)(NGR * 656)};

  for (int L = 0; L < 3; L++) {
    float* sums = sums3 + L * 128;
    if (L == 0)
      gemm_xw<128, false><<<NTOT / 256, 256, 0, stream>>>(x, Wk[0], bufXW, NTOT);
    else
      gemm_xw<64, true><<<NTOT / 256, 256, 0, stream>>>(bufX, Wk[L], bufXW, NTOT);
    edge_agg<<<8 * NGR, 1024, 0, stream>>>(csr, rs, dinv_g, bufXW, bk[L], bufH, sums);
    score_kernel<<<4 * NGR, 256, 0, stream>>>(bufH, sums, gk[L], btk[L], pk[L],
                                              dinv_g, score, stanh_g, invn[L]);
    topk_kernel<<<4 * NGR, 1024, 0, stream>>>(score, snext_g, kk[L]);
    pool_kernel<<<8 * NGR, 256, 0, stream>>>(bufH, sums, gk[L], btk[L],
                                             stanh_g, snext_g, csr, rs,
                                             (L < 2) ? bufX : nullptr, dinv_g,
                                             readout, kk[L], invn[L],
                                             (L < 2) ? 1 : 0);
  }
  final_linear<<<5, 256, 0, stream>>>(readout, Wm, bm, out);
}